// Round 3
// baseline (451.513 us; speedup 1.0000x reference)
//
#include <hip/hip_runtime.h>
#include <hip/hip_bf16.h>

#define T_SEQ 4096
#define HIDDEN 2560
#define NH 8
#define NKV 4
#define HD 256
#define WINDOW 1024
#define SM_SCALE 0.0625f

typedef __bf16 bf16x8 __attribute__((ext_vector_type(8)));
typedef float f32x4 __attribute__((ext_vector_type(4)));
typedef __hip_bfloat16 bf16;

#define GLOAD_LDS(g, l) \
  __builtin_amdgcn_global_load_lds((const __attribute__((address_space(1))) void*)(g), \
                                   (__attribute__((address_space(3))) void*)(l), 16, 0, 0)

// ---------- fp32 -> bf16 elementwise convert (8 elems/thread) ----------
__global__ __launch_bounds__(256) void k_f2b(
    const float* __restrict__ src, bf16* __restrict__ dst)
{
  const size_t i = (size_t)blockIdx.x * 256 + threadIdx.x;
  const float4 a = ((const float4*)src)[i * 2];
  const float4 b = ((const float4*)src)[i * 2 + 1];
  bf16 tmp[8];
  tmp[0] = __float2bfloat16(a.x); tmp[1] = __float2bfloat16(a.y);
  tmp[2] = __float2bfloat16(a.z); tmp[3] = __float2bfloat16(a.w);
  tmp[4] = __float2bfloat16(b.x); tmp[5] = __float2bfloat16(b.y);
  tmp[6] = __float2bfloat16(b.z); tmp[7] = __float2bfloat16(b.w);
  *(bf16x8*)(dst + i * 8) = *(bf16x8*)tmp;
}

// ---------- fp32 src -> bf16 dst 64x64-tile transpose: dst[c][r] = (bf16)src[r][c] ----------
__global__ __launch_bounds__(256) void k_transpose_f2b(
    const float* __restrict__ src, bf16* __restrict__ dst, int srs, int drs)
{
  __shared__ bf16 t[64 * 72];  // +8 pad breaks bank conflicts on transposed read
  const int tid = threadIdx.x;
  const int c0 = blockIdx.x * 64;
  const int r0 = blockIdx.y * 64;
  const int rr = tid >> 3;
  const int cc = (tid & 7) * 8;
#pragma unroll
  for (int p = 0; p < 2; ++p) {
    const float* sp = src + (size_t)(r0 + p * 32 + rr) * srs + c0 + cc;
    const float4 a = *(const float4*)sp;
    const float4 b = *(const float4*)(sp + 4);
    bf16* tp = &t[(p * 32 + rr) * 72 + cc];
    tp[0] = __float2bfloat16(a.x); tp[1] = __float2bfloat16(a.y);
    tp[2] = __float2bfloat16(a.z); tp[3] = __float2bfloat16(a.w);
    tp[4] = __float2bfloat16(b.x); tp[5] = __float2bfloat16(b.y);
    tp[6] = __float2bfloat16(b.z); tp[7] = __float2bfloat16(b.w);
  }
  __syncthreads();
#pragma unroll
  for (int p = 0; p < 2; ++p) {
    const int n = p * 32 + rr;
    bf16x8 v;
#pragma unroll
    for (int i = 0; i < 8; ++i) v[i] = ((const __bf16*)t)[(cc + i) * 72 + n];
    *(bf16x8*)(dst + (size_t)(c0 + n) * drs + r0 + cc) = v;
  }
}

// ---------- bf16 64x64-tile transpose (for V): dst[c][r] = src[r][c] ----------
__global__ __launch_bounds__(256) void k_transpose(
    const bf16* __restrict__ src, bf16* __restrict__ dst,
    int srs, int drs, long src_zoff, long dst_zoff)
{
  __shared__ bf16 t[64 * 72];
  src += (size_t)blockIdx.z * src_zoff;
  dst += (size_t)blockIdx.z * dst_zoff;
  const int tid = threadIdx.x;
  const int c0 = blockIdx.x * 64;
  const int r0 = blockIdx.y * 64;
  const int rr = tid >> 3;
  const int cc = (tid & 7) * 8;
#pragma unroll
  for (int p = 0; p < 2; ++p) {
    bf16x8 v = *(const bf16x8*)(src + (size_t)(r0 + p * 32 + rr) * srs + c0 + cc);
    *(bf16x8*)(&t[(p * 32 + rr) * 72 + cc]) = v;
  }
  __syncthreads();
#pragma unroll
  for (int p = 0; p < 2; ++p) {
    const int n = p * 32 + rr;
    bf16x8 v;
#pragma unroll
    for (int i = 0; i < 8; ++i) v[i] = ((const __bf16*)t)[(cc + i) * 72 + n];
    *(bf16x8*)(dst + (size_t)(c0 + n) * drs + r0 + cc) = v;
  }
}

// ---------- 256x256-tile 8-phase bf16 GEMM (m201 template): C = A[M][K] * Bt[N][K]^T ----------
template <typename OutT>
__global__ __launch_bounds__(512, 2) void k_gemm8(
    const bf16* __restrict__ A, const bf16* __restrict__ Bt,
    OutT* __restrict__ C, int M, int N, int K)
{
  __shared__ bf16 As[2 * 256 * 64];
  __shared__ bf16 Bs[2 * 256 * 64];
  constexpr int BUFB = 256 * 64 * 2;  // bytes per buffer

  const int tid = threadIdx.x;
  const int wave = tid >> 6;
  const int lane = tid & 63;
  const int l16 = lane & 15;
  const int quad = lane >> 4;
  const int wm = wave >> 2;   // 0..1 -> rows wm*128..+127
  const int wn = wave & 3;    // 0..3 -> cols wn*64..+63

  // XCD-aware bijective swizzle (both launches have nwg % 8 == 0)
  int id = blockIdx.y * gridDim.x + blockIdx.x;
  const int nwg = gridDim.x * gridDim.y;
  const int chunk = nwg >> 3;
  id = (id & 7) * chunk + (id >> 3);
  const int bx = id % gridDim.x;
  const int by = id / gridDim.x;
  const int m0 = by * 256;
  const int n0 = bx * 256;

  const int NT = K >> 6;           // K-tiles of 64
  const int xorv = (l16 & 7) << 4; // T2 swizzle key for fragment reads

  // staging source bases (per-lane, pre-swizzled: col chunk = (l&7)^(l>>3))
  const bf16* srcA = A + (size_t)(m0 + wave * 16 + (lane >> 3)) * K + ((lane & 7) ^ (lane >> 3)) * 8;
  const bf16* srcB = Bt + (size_t)(n0 + wave * 16 + (lane >> 3)) * K + ((lane & 7) ^ (lane >> 3)) * 8;

  auto stage_a = [&](int buf, int h, int kt) {
    const bf16* sp = srcA + (size_t)(h * 128) * K + kt * 64;
    char* dp = (char*)As + buf * BUFB + h * 16384 + wave * 2048;  // wave-uniform; HW adds lane*16
    GLOAD_LDS(sp, dp);
    GLOAD_LDS(sp + (size_t)8 * K, dp + 1024);
  };
  auto stage_b = [&](int buf, int h, int kt) {
    const bf16* sp = srcB + (size_t)(h * 128) * K + kt * 64;
    char* dp = (char*)Bs + buf * BUFB + h * 16384 + wave * 2048;
    GLOAD_LDS(sp, dp);
    GLOAD_LDS(sp + (size_t)8 * K, dp + 1024);
  };

  bf16x8 afr[8][2];  // A row-frags 0..7 x k-slice 0..1
  bf16x8 bfr[4][2];  // B col-frags 0..3 x k-slice
  f32x4 acc[8][4] = {};

  // prologue: kt0 fully, kt1 A-halves; wait for kt0 (leave 4 loads in flight)
  stage_a(0, 0, 0); stage_a(0, 1, 0);
  stage_b(0, 0, 0); stage_b(0, 1, 0);
  stage_a(1, 0, 1); stage_a(1, 1, 1);
  asm volatile("s_waitcnt vmcnt(4)" ::: "memory");
  __builtin_amdgcn_s_barrier();

  for (int kt = 0; kt < NT; ++kt) {
    const int bsel = kt & 1;
    const char* Ab = (const char*)As + bsel * BUFB;
    const char* Bb = (const char*)Bs + bsel * BUFB;

    auto read_a = [&](int I0) {
#pragma unroll
      for (int ii = 0; ii < 4; ++ii)
#pragma unroll
        for (int s = 0; s < 2; ++s)
          afr[I0 + ii][s] = *(const bf16x8*)(
              Ab + (wm * 128 + (I0 + ii) * 16 + l16) * 128 + ((s * 64 + quad * 16) ^ xorv));
    };
    auto read_b = [&](int J0) {
#pragma unroll
      for (int jj = 0; jj < 2; ++jj)
#pragma unroll
        for (int s = 0; s < 2; ++s)
          bfr[J0 + jj][s] = *(const bf16x8*)(
              Bb + (wn * 64 + (J0 + jj) * 16 + l16) * 128 + ((s * 64 + quad * 16) ^ xorv));
    };
    auto mfma_quad = [&](int I0, int J0) {
#pragma unroll
      for (int ii = 0; ii < 4; ++ii)
#pragma unroll
        for (int jj = 0; jj < 2; ++jj)
#pragma unroll
          for (int s = 0; s < 2; ++s)
            acc[I0 + ii][J0 + jj] = __builtin_amdgcn_mfma_f32_16x16x32_bf16(
                afr[I0 + ii][s], bfr[J0 + jj][s], acc[I0 + ii][J0 + jj], 0, 0, 0);
    };

    // ---- phase 1: read a0+b0 (12 ds_read), stage Bh0(kt+1), mfma a0*b0
    read_a(0);
    read_b(0);
    if (kt + 1 < NT) stage_b(bsel ^ 1, 0, kt + 1);
    asm volatile("s_waitcnt lgkmcnt(8)" ::: "memory");
    __builtin_amdgcn_s_barrier();
    asm volatile("s_waitcnt lgkmcnt(0)" ::: "memory");
    __builtin_amdgcn_sched_barrier(0);
    __builtin_amdgcn_s_setprio(1);
    mfma_quad(0, 0);
    __builtin_amdgcn_s_setprio(0);
    __builtin_amdgcn_s_barrier();
    // ---- phase 2: read a1, stage Bh1(kt+1), mfma a1*b0
    read_a(4);
    if (kt + 1 < NT) stage_b(bsel ^ 1, 1, kt + 1);
    __builtin_amdgcn_s_barrier();
    asm volatile("s_waitcnt lgkmcnt(0)" ::: "memory");
    __builtin_amdgcn_sched_barrier(0);
    __builtin_amdgcn_s_setprio(1);
    mfma_quad(4, 0);
    __builtin_amdgcn_s_setprio(0);
    __builtin_amdgcn_s_barrier();
    // ---- phase 3: read b1, stage Ah0(kt+2) (A reads of kt done after P2), mfma a1*b1
    read_b(2);
    if (kt + 2 < NT) stage_a(bsel, 0, kt + 2);
    __builtin_amdgcn_s_barrier();
    asm volatile("s_waitcnt lgkmcnt(0)" ::: "memory");
    __builtin_amdgcn_sched_barrier(0);
    __builtin_amdgcn_s_setprio(1);
    mfma_quad(4, 2);
    __builtin_amdgcn_s_setprio(0);
    __builtin_amdgcn_s_barrier();
    // ---- phase 4: stage Ah1(kt+2), mfma a0*b1, counted boundary wait
    if (kt + 2 < NT) stage_a(bsel, 1, kt + 2);
    __builtin_amdgcn_s_barrier();
    __builtin_amdgcn_s_setprio(1);
    mfma_quad(0, 2);
    __builtin_amdgcn_s_setprio(0);
    if (kt + 2 < NT) {
      asm volatile("s_waitcnt vmcnt(4)" ::: "memory");
    } else if (kt + 1 < NT) {
      asm volatile("s_waitcnt vmcnt(0)" ::: "memory");
    }
    __builtin_amdgcn_s_barrier();
  }

  // epilogue: C/D layout col = lane&15, row = quad*4 + reg
#pragma unroll
  for (int i = 0; i < 8; ++i)
#pragma unroll
    for (int j = 0; j < 4; ++j) {
      const int col = n0 + wn * 64 + j * 16 + l16;
#pragma unroll
      for (int r = 0; r < 4; ++r) {
        const int row = m0 + wm * 128 + i * 16 + quad * 4 + r;
        if constexpr (__is_same(OutT, float))
          C[(size_t)row * N + col] = acc[i][j][r];
        else
          C[(size_t)row * N + col] = __float2bfloat16(acc[i][j][r]);
      }
    }
}

// ---------- RMSNorm (fp32) + RoPE for q (slots 0..7) and k (slots 8..11) ----------
__global__ __launch_bounds__(64) void k_norm_rope(
    const bf16* __restrict__ qkv, const int* __restrict__ positions,
    const float* __restrict__ qw, const float* __restrict__ kw,
    bf16* __restrict__ q_r, bf16* __restrict__ k_r)
{
  const int t = blockIdx.x;
  const int slot = blockIdx.y;
  const int lane = threadIdx.x;
  const bf16* base = qkv + (size_t)t * 4096 + slot * 256;
  float x[4];
#pragma unroll
  for (int i = 0; i < 4; ++i) x[i] = __bfloat162float(base[lane + 64 * i]);
  float ss = x[0] * x[0] + x[1] * x[1] + x[2] * x[2] + x[3] * x[3];
#pragma unroll
  for (int off = 1; off < 64; off <<= 1) ss += __shfl_xor(ss, off, 64);
  const float rn = rsqrtf(ss * (1.0f / 256.0f) + 1e-6f);
  const float* w = (slot < 8) ? qw : kw;
  float nv[4];
#pragma unroll
  for (int i = 0; i < 4; ++i)
    nv[i] = x[i] * rn * (1.0f + w[lane + 64 * i]);
  const float p = (float)positions[t];
  const float C_LOG2_10K_128 = 13.287712379549449f / 128.0f;
  const float f0 = p * exp2f(-(float)lane * C_LOG2_10K_128);
  const float f1 = p * exp2f(-(float)(lane + 64) * C_LOG2_10K_128);
  const float c0 = cosf(f0), s0 = sinf(f0);
  const float c1 = cosf(f1), s1 = sinf(f1);
  const float o0 = nv[0] * c0 - nv[2] * s0;
  const float o2 = nv[2] * c0 + nv[0] * s0;
  const float o1 = nv[1] * c1 - nv[3] * s1;
  const float o3 = nv[3] * c1 + nv[1] * s1;
  bf16* dst = (slot < 8) ? (q_r + ((size_t)slot * T_SEQ + t) * 256)
                         : (k_r + ((size_t)(slot - 8) * T_SEQ + t) * 256);
  dst[lane]       = __float2bfloat16(o0);
  dst[lane + 64]  = __float2bfloat16(o1);
  dst[lane + 128] = __float2bfloat16(o2);
  dst[lane + 192] = __float2bfloat16(o3);
}

// ---------- flash attention, sliding window, GQA ----------
// q_r [8][T][256], k_r [4][T][256], vt [4][256][T], attn [T][2048]
// 32 q-rows per wave (2x16 MFMA blocks share every K/V fragment -> LDS reads
// per FLOP halved vs 16 q/wave; kernel was LDS-read-BW-bound at 12.5% MfmaUtil).
// 2-wave 128-thread blocks, 512-block grid (2 blocks/CU, barriers don't idle CU).
// T1 per-head XCD swizzle; T2 XOR swizzles (both-sides w/ pre-swizzled gload src);
// dbuf staging w/ counted vmcnt(16); T13 defer-max; interior-tile mask fast path;
// fully-masked tiles skip compute (barriers kept balanced).
__global__ __launch_bounds__(128) void k_attn(
    const bf16* __restrict__ q_r, const bf16* __restrict__ k_r,
    const bf16* __restrict__ vt, bf16* __restrict__ attn)
{
  __shared__ bf16 Ks[2][32 * 256];    // [key][d], d-chunk xor (row&7)
  __shared__ bf16 Vts[2][256 * 32];   // [d][key], key-chunk xor (d&3)
  __shared__ bf16 Ps[4 * 512];        // per (wave,qb) P: [16 q][32 key]
  const int tid = threadIdx.x;
  const int w = tid >> 6;
  const int lane = tid & 63;
  const int l16 = lane & 15;
  const int quad = lane >> 4;
  // XCD swizzle: head k's 64 q-tiles all land on XCD k (K/V L2-resident)
  const int bid = blockIdx.y * gridDim.x + blockIdx.x;   // 512 blocks
  const int orig = (bid & 7) * 64 + (bid >> 3);
  const int q0 = (orig & 63) * 64;
  const int h = orig >> 6;
  const int kh = h >> 1;
  const int qw0 = q0 + w * 32;   // this wave's 32 q-rows

  // Q A-fragments in registers: 2 q-blocks x 8 k-steps
  bf16x8 qf[2][8];
#pragma unroll
  for (int qb = 0; qb < 2; ++qb) {
    const bf16* qbp = q_r + ((size_t)h * T_SEQ + qw0 + qb * 16 + l16) * HD + quad * 8;
#pragma unroll
    for (int s = 0; s < 8; ++s) qf[qb][s] = *(const bf16x8*)(qbp + s * 32);
  }
  f32x4 O[2][16] = {};
  float mrow[2][4], lrow[2][4];
#pragma unroll
  for (int qb = 0; qb < 2; ++qb)
#pragma unroll
    for (int r = 0; r < 4; ++r) { mrow[qb][r] = -1e30f; lrow[qb][r] = 0.f; }

  // staging thread mapping (128 threads):
  // K: instr p -> LDS row p*4 + (tid>>5), chunk tid&31; pre-swizzled src col
  // V: instr p -> LDS row d = p*32 + (tid>>2), chunk tid&3; pre-swizzled src key
  const int rK = tid >> 5;   // 0..3
  const int cK = tid & 31;
  const int rV = tid >> 2;   // 0..31
  const int cV = tid & 3;
  const bf16* kgb0 = k_r + ((size_t)kh * T_SEQ + rK) * HD + ((cK ^ rK) * 8);       // even p
  const bf16* kgb1 = k_r + ((size_t)kh * T_SEQ + rK) * HD + ((cK ^ rK ^ 4) * 8);   // odd p
  const bf16* vgb  = vt + ((size_t)kh * HD + rV) * T_SEQ + ((cV ^ (rV & 3)) * 8);

  auto stage = [&](int buf, int j) {
    char* kl = (char*)&Ks[buf][0] + w * 1024;
    char* vl = (char*)&Vts[buf][0] + w * 1024;
#pragma unroll
    for (int p = 0; p < 8; ++p) {
      const bf16* kg = ((p & 1) ? kgb1 : kgb0) + (size_t)(j + p * 4) * HD;
      GLOAD_LDS(kg, kl + p * 2048);
    }
#pragma unroll
    for (int p = 0; p < 8; ++p) {
      const bf16* vg = vgb + (size_t)p * 32 * T_SEQ + j;
      GLOAD_LDS(vg, vl + p * 2048);
    }
  };

  const int jstart = ((q0 > 1023) ? (q0 - 1023) : 0) & ~31;
  const int jlast = q0 + 32;
  const int k7 = l16 & 7;
  const int v3 = l16 & 3;
  bf16* Pq[2] = { Ps + (w * 2) * 512, Ps + (w * 2 + 1) * 512 };

  stage(0, jstart);
  int it = 0;
  for (int j0 = jstart; j0 <= jlast; j0 += 32, ++it) {
    const int cur = it & 1;
    if (j0 + 32 <= jlast) {
      stage(cur ^ 1, j0 + 32);                          // issue next tile early
      asm volatile("s_waitcnt vmcnt(16)" ::: "memory"); // cur landed; next in flight
    } else {
      asm volatile("s_waitcnt vmcnt(0)" ::: "memory");
    }
    __builtin_amdgcn_s_barrier();

    // wave-level tile classification (wave-uniform branches)
    const bool any_valid = (j0 <= qw0 + 31) && (j0 + 31 >= qw0 - (WINDOW - 1));
    if (any_valid) {
      const bf16* Kc = Ks[cur];
      const bf16* Vc = Vts[cur];

      // S = Q K^T : 2 q-blocks x 32 keys; kf fragments shared by both q-blocks
      f32x4 sa[2][2] = {};
#pragma unroll
      for (int s = 0; s < 8; ++s) {
        const int ch = ((s * 4 + quad) ^ k7) * 8;
        bf16x8 kf0 = *(const bf16x8*)(Kc + l16 * 256 + ch);
        bf16x8 kf1 = *(const bf16x8*)(Kc + (16 + l16) * 256 + ch);
        sa[0][0] = __builtin_amdgcn_mfma_f32_16x16x32_bf16(qf[0][s], kf0, sa[0][0], 0, 0, 0);
        sa[0][1] = __builtin_amdgcn_mfma_f32_16x16x32_bf16(qf[0][s], kf1, sa[0][1], 0, 0, 0);
        sa[1][0] = __builtin_amdgcn_mfma_f32_16x16x32_bf16(qf[1][s], kf0, sa[1][0], 0, 0, 0);
        sa[1][1] = __builtin_amdgcn_mfma_f32_16x16x32_bf16(qf[1][s], kf1, sa[1][1], 0, 0, 0);
      }

      const bool interior = (j0 + 31 <= qw0) && (qw0 + 31 - j0 < WINDOW);
      float sm[2][2][4];
      if (interior) {
#pragma unroll
        for (int qb = 0; qb < 2; ++qb)
#pragma unroll
          for (int r = 0; r < 4; ++r) {
            sm[qb][0][r] = sa[qb][0][r] * SM_SCALE;
            sm[qb][1][r] = sa[qb][1][r] * SM_SCALE;
          }
      } else {
#pragma unroll
        for (int qb = 0; qb < 2; ++qb)
#pragma unroll
          for (int r = 0; r < 4; ++r) {
            const int i = qw0 + qb * 16 + quad * 4 + r;
            const int ja = j0 + l16;
            const int jb = ja + 16;
            sm[qb][0][r] = ((ja <= i) && (i - ja < WINDOW)) ? sa[qb][0][r] * SM_SCALE : -1e30f;
            sm[qb][1][r] = ((jb <= i) && (i - jb < WINDOW)) ? sa[qb][1][r] * SM_SCALE : -1e30f;
          }
      }
      // per-row tile max (16-lane reduce) + T13 defer-max check
      float mx[2][4];
      bool ok = true;
#pragma unroll
      for (int qb = 0; qb < 2; ++qb)
#pragma unroll
        for (int r = 0; r < 4; ++r) {
          float m2 = fmaxf(sm[qb][0][r], sm[qb][1][r]);
#pragma unroll
          for (int off = 1; off < 16; off <<= 1) m2 = fmaxf(m2, __shfl_xor(m2, off, 64));
          mx[qb][r] = m2;
          ok = ok && (m2 <= mrow[qb][r] + 8.0f);
        }
      if (!__all(ok)) {
#pragma unroll
        for (int qb = 0; qb < 2; ++qb)
#pragma unroll
          for (int r = 0; r < 4; ++r) {
            const float mnew = fmaxf(mrow[qb][r], mx[qb][r]);
            const float alpha = __expf(mrow[qb][r] - mnew);
            lrow[qb][r] *= alpha;
#pragma unroll
            for (int n = 0; n < 16; ++n) O[qb][n][r] *= alpha;
            mrow[qb][r] = mnew;
          }
      }
      // P = exp(S - m)  (masked lanes: exp(-1e30 - m) flushes to 0)
#pragma unroll
      for (int qb = 0; qb < 2; ++qb)
#pragma unroll
        for (int r = 0; r < 4; ++r) {
          const float p0 = __expf(sm[qb][0][r] - mrow[qb][r]);  // bounded by e^8
          const float p1 = __expf(sm[qb][1][r] - mrow[qb][r]);
          float rs = p0 + p1;
#pragma unroll
          for (int off = 1; off < 16; off <<= 1) rs += __shfl_xor(rs, off, 64);
          lrow[qb][r] += rs;
          const int prow = quad * 4 + r;
          Pq[qb][prow * 32 + (((l16 >> 3) ^ quad) * 8) + (l16 & 7)]       = __float2bfloat16(p0);
          Pq[qb][prow * 32 + ((((l16 >> 3) + 2) ^ quad) * 8) + (l16 & 7)] = __float2bfloat16(p1);
        }
      // C-layout -> A-layout round trip through per-(wave,qb) LDS (wave-internal)
      asm volatile("s_waitcnt lgkmcnt(0)" ::: "memory");
      __builtin_amdgcn_sched_barrier(0);
      bf16x8 pf0 = *(const bf16x8*)(Pq[0] + l16 * 32 + ((quad ^ (l16 >> 2)) * 8));
      bf16x8 pf1 = *(const bf16x8*)(Pq[1] + l16 * 32 + ((quad ^ (l16 >> 2)) * 8));
#pragma unroll
      for (int n = 0; n < 16; ++n) {
        bf16x8 vf = *(const bf16x8*)(Vc + (n * 16 + l16) * 32 + ((quad ^ v3) * 8));
        O[0][n] = __builtin_amdgcn_mfma_f32_16x16x32_bf16(pf0, vf, O[0][n], 0, 0, 0);
        O[1][n] = __builtin_amdgcn_mfma_f32_16x16x32_bf16(pf1, vf, O[1][n], 0, 0, 0);
      }
    }
    __builtin_amdgcn_s_barrier();   // reads of cur done; next iter restages it
  }
  // epilogue: O /= l, write [T][H*D]
#pragma unroll
  for (int qb = 0; qb < 2; ++qb)
#pragma unroll
    for (int r = 0; r < 4; ++r) {
      const float inv = 1.0f / lrow[qb][r];
      const size_t row = qw0 + qb * 16 + quad * 4 + r;
#pragma unroll
      for (int n = 0; n < 16; ++n)
        attn[row * (NH * HD) + h * HD + n * 16 + l16] = __float2bfloat16(O[qb][n][r] * inv);
    }
}

extern "C" void kernel_launch(void* const* d_in, const int* in_sizes, int n_in,
                              void* d_out, int out_size, void* d_ws, size_t ws_size,
                              hipStream_t stream)
{
  const float* x  = (const float*)d_in[0];
  const int* pos  = (const int*)d_in[1];
  const float* Wq = (const float*)d_in[2];
  const float* Wk = (const float*)d_in[3];
  const float* Wv = (const float*)d_in[4];
  const float* Wo = (const float*)d_in[5];
  const float* qw = (const float*)d_in[6];
  const float* kw = (const float*)d_in[7];
  float* out = (float*)d_out;   // reference output dtype is FP32

  char* ws = (char*)d_ws;
  size_t off = 0;
  bf16* Wqkv_t = (bf16*)(ws + off); off += (size_t)4096 * 2560 * 2;  // dead after GEMM1; reused as attn_b
  bf16* Wo_t   = (bf16*)(ws + off); off += (size_t)2560 * 2048 * 2;
  bf16* qkv_b  = (bf16*)(ws + off); off += (size_t)4096 * 4096 * 2;
  bf16* q_r    = (bf16*)(ws + off); off += (size_t)8 * 4096 * 256 * 2;
  bf16* k_r    = (bf16*)(ws + off); off += (size_t)4 * 4096 * 256 * 2;
  bf16* v_t    = (bf16*)(ws + off); off += (size_t)4 * 256 * 4096 * 2;
  bf16* attn_b = Wqkv_t;
  // x_bf16 (21 MB) aliases q_r (16.8 MB) + head of k_r: x_b dies at GEMM1,
  // q_r/k_r are written only after GEMM1 completes.
  bf16* x_b = q_r;
  if (ws_size < off) return;  // insufficient workspace -> fail loudly

  // fp32 -> bf16 conversions: x elementwise, weights fused into B^T transposes
  k_f2b<<<dim3((4096 * 2560) / (256 * 8)), 256, 0, stream>>>(x, x_b);
  k_transpose_f2b<<<dim3(32, 40), 256, 0, stream>>>(Wq, Wqkv_t, 2048, 2560);
  k_transpose_f2b<<<dim3(16, 40), 256, 0, stream>>>(Wk, Wqkv_t + (size_t)2048 * 2560, 1024, 2560);
  k_transpose_f2b<<<dim3(16, 40), 256, 0, stream>>>(Wv, Wqkv_t + (size_t)3072 * 2560, 1024, 2560);
  k_transpose_f2b<<<dim3(40, 32), 256, 0, stream>>>(Wo, Wo_t, 2560, 2048);
  // fused QKV projection: [4096,2560] x [2560,4096] -> [4096,4096] (bf16 out), 256 blocks
  k_gemm8<bf16><<<dim3(16, 16), 512, 0, stream>>>(x_b, Wqkv_t, qkv_b, 4096, 4096, 2560);
  // RMSNorm + RoPE for q,k (overwrites x_b region -- x_b is dead now)
  k_norm_rope<<<dim3(4096, 12), 64, 0, stream>>>(qkv_b, pos, qw, kw, q_r, k_r);
  // V transpose: qkv_b[t][3072+kh*256+d] -> v_t[kh][d][t]
  k_transpose<<<dim3(4, 64, 4), 256, 0, stream>>>(qkv_b + 3072, v_t, 4096, 4096, 256, (long)256 * 4096);
  // flash attention: 512 blocks x 128 threads (2 waves, 32 q-rows each)
  k_attn<<<dim3(64, 8), 128, 0, stream>>>(q_r, k_r, v_t, attn_b);
  // output projection: [4096,2048] x [2048,2560] -> out (FP32 out), 160 blocks
  k_gemm8<float><<<dim3(10, 16), 512, 0, stream>>>(attn_b, Wo_t, out, 4096, 2560, 2048);
}

// Round 4
// 384.336 us; speedup vs baseline: 1.1748x; 1.1748x over previous
//
#include <hip/hip_runtime.h>
#include <hip/hip_bf16.h>

#define T_SEQ 4096
#define HIDDEN 2560
#define NH 8
#define NKV 4
#define HD 256
#define WINDOW 1024
#define SM_SCALE 0.0625f

typedef __bf16 bf16x8 __attribute__((ext_vector_type(8)));
typedef float f32x4 __attribute__((ext_vector_type(4)));
typedef __hip_bfloat16 bf16;

#define GLOAD_LDS(g, l) \
  __builtin_amdgcn_global_load_lds((const __attribute__((address_space(1))) void*)(g), \
                                   (__attribute__((address_space(3))) void*)(l), 16, 0, 0)

// ---------- fp32 -> bf16 elementwise convert (8 elems/thread) ----------
__global__ __launch_bounds__(256) void k_f2b(
    const float* __restrict__ src, bf16* __restrict__ dst)
{
  const size_t i = (size_t)blockIdx.x * 256 + threadIdx.x;
  const float4 a = ((const float4*)src)[i * 2];
  const float4 b = ((const float4*)src)[i * 2 + 1];
  bf16 tmp[8];
  tmp[0] = __float2bfloat16(a.x); tmp[1] = __float2bfloat16(a.y);
  tmp[2] = __float2bfloat16(a.z); tmp[3] = __float2bfloat16(a.w);
  tmp[4] = __float2bfloat16(b.x); tmp[5] = __float2bfloat16(b.y);
  tmp[6] = __float2bfloat16(b.z); tmp[7] = __float2bfloat16(b.w);
  *(bf16x8*)(dst + i * 8) = *(bf16x8*)tmp;
}

// ---------- fp32 src -> bf16 dst 64x64-tile transpose: dst[c][r] = (bf16)src[r][c] ----------
__global__ __launch_bounds__(256) void k_transpose_f2b(
    const float* __restrict__ src, bf16* __restrict__ dst, int srs, int drs)
{
  __shared__ bf16 t[64 * 72];  // +8 pad breaks bank conflicts on transposed read
  const int tid = threadIdx.x;
  const int c0 = blockIdx.x * 64;
  const int r0 = blockIdx.y * 64;
  const int rr = tid >> 3;
  const int cc = (tid & 7) * 8;
#pragma unroll
  for (int p = 0; p < 2; ++p) {
    const float* sp = src + (size_t)(r0 + p * 32 + rr) * srs + c0 + cc;
    const float4 a = *(const float4*)sp;
    const float4 b = *(const float4*)(sp + 4);
    bf16* tp = &t[(p * 32 + rr) * 72 + cc];
    tp[0] = __float2bfloat16(a.x); tp[1] = __float2bfloat16(a.y);
    tp[2] = __float2bfloat16(a.z); tp[3] = __float2bfloat16(a.w);
    tp[4] = __float2bfloat16(b.x); tp[5] = __float2bfloat16(b.y);
    tp[6] = __float2bfloat16(b.z); tp[7] = __float2bfloat16(b.w);
  }
  __syncthreads();
#pragma unroll
  for (int p = 0; p < 2; ++p) {
    const int n = p * 32 + rr;
    bf16x8 v;
#pragma unroll
    for (int i = 0; i < 8; ++i) v[i] = ((const __bf16*)t)[(cc + i) * 72 + n];
    *(bf16x8*)(dst + (size_t)(c0 + n) * drs + r0 + cc) = v;
  }
}

// ---------- bf16 64x64-tile transpose (for V): dst[c][r] = src[r][c] ----------
__global__ __launch_bounds__(256) void k_transpose(
    const bf16* __restrict__ src, bf16* __restrict__ dst,
    int srs, int drs, long src_zoff, long dst_zoff)
{
  __shared__ bf16 t[64 * 72];
  src += (size_t)blockIdx.z * src_zoff;
  dst += (size_t)blockIdx.z * dst_zoff;
  const int tid = threadIdx.x;
  const int c0 = blockIdx.x * 64;
  const int r0 = blockIdx.y * 64;
  const int rr = tid >> 3;
  const int cc = (tid & 7) * 8;
#pragma unroll
  for (int p = 0; p < 2; ++p) {
    bf16x8 v = *(const bf16x8*)(src + (size_t)(r0 + p * 32 + rr) * srs + c0 + cc);
    *(bf16x8*)(&t[(p * 32 + rr) * 72 + cc]) = v;
  }
  __syncthreads();
#pragma unroll
  for (int p = 0; p < 2; ++p) {
    const int n = p * 32 + rr;
    bf16x8 v;
#pragma unroll
    for (int i = 0; i < 8; ++i) v[i] = ((const __bf16*)t)[(cc + i) * 72 + n];
    *(bf16x8*)(dst + (size_t)(c0 + n) * drs + r0 + cc) = v;
  }
}

// ---------- 256x256-tile 8-phase bf16 GEMM (m201 template): C = A[M][K] * Bt[N][K]^T ----------
template <typename OutT>
__global__ __launch_bounds__(512, 2) void k_gemm8(
    const bf16* __restrict__ A, const bf16* __restrict__ Bt,
    OutT* __restrict__ C, int M, int N, int K)
{
  __shared__ bf16 As[2 * 256 * 64];
  __shared__ bf16 Bs[2 * 256 * 64];
  constexpr int BUFB = 256 * 64 * 2;  // bytes per buffer

  const int tid = threadIdx.x;
  const int wave = tid >> 6;
  const int lane = tid & 63;
  const int l16 = lane & 15;
  const int quad = lane >> 4;
  const int wm = wave >> 2;   // 0..1 -> rows wm*128..+127
  const int wn = wave & 3;    // 0..3 -> cols wn*64..+63

  // XCD-aware bijective swizzle (both launches have nwg % 8 == 0)
  int id = blockIdx.y * gridDim.x + blockIdx.x;
  const int nwg = gridDim.x * gridDim.y;
  const int chunk = nwg >> 3;
  id = (id & 7) * chunk + (id >> 3);
  const int bx = id % gridDim.x;
  const int by = id / gridDim.x;
  const int m0 = by * 256;
  const int n0 = bx * 256;

  const int NT = K >> 6;           // K-tiles of 64
  const int xorv = (l16 & 7) << 4; // T2 swizzle key for fragment reads

  // staging source bases (per-lane, pre-swizzled: col chunk = (l&7)^(l>>3))
  const bf16* srcA = A + (size_t)(m0 + wave * 16 + (lane >> 3)) * K + ((lane & 7) ^ (lane >> 3)) * 8;
  const bf16* srcB = Bt + (size_t)(n0 + wave * 16 + (lane >> 3)) * K + ((lane & 7) ^ (lane >> 3)) * 8;

  auto stage_a = [&](int buf, int h, int kt) {
    const bf16* sp = srcA + (size_t)(h * 128) * K + kt * 64;
    char* dp = (char*)As + buf * BUFB + h * 16384 + wave * 2048;  // wave-uniform; HW adds lane*16
    GLOAD_LDS(sp, dp);
    GLOAD_LDS(sp + (size_t)8 * K, dp + 1024);
  };
  auto stage_b = [&](int buf, int h, int kt) {
    const bf16* sp = srcB + (size_t)(h * 128) * K + kt * 64;
    char* dp = (char*)Bs + buf * BUFB + h * 16384 + wave * 2048;
    GLOAD_LDS(sp, dp);
    GLOAD_LDS(sp + (size_t)8 * K, dp + 1024);
  };

  bf16x8 afr[8][2];  // A row-frags 0..7 x k-slice 0..1
  bf16x8 bfr[4][2];  // B col-frags 0..3 x k-slice
  f32x4 acc[8][4] = {};

  // prologue: kt0 fully, kt1 A-halves; wait for kt0 (leave 4 loads in flight)
  stage_a(0, 0, 0); stage_a(0, 1, 0);
  stage_b(0, 0, 0); stage_b(0, 1, 0);
  stage_a(1, 0, 1); stage_a(1, 1, 1);
  asm volatile("s_waitcnt vmcnt(4)" ::: "memory");
  __builtin_amdgcn_s_barrier();

  for (int kt = 0; kt < NT; ++kt) {
    const int bsel = kt & 1;
    const char* Ab = (const char*)As + bsel * BUFB;
    const char* Bb = (const char*)Bs + bsel * BUFB;

    auto read_a = [&](int I0) {
#pragma unroll
      for (int ii = 0; ii < 4; ++ii)
#pragma unroll
        for (int s = 0; s < 2; ++s)
          afr[I0 + ii][s] = *(const bf16x8*)(
              Ab + (wm * 128 + (I0 + ii) * 16 + l16) * 128 + ((s * 64 + quad * 16) ^ xorv));
    };
    auto read_b = [&](int J0) {
#pragma unroll
      for (int jj = 0; jj < 2; ++jj)
#pragma unroll
        for (int s = 0; s < 2; ++s)
          bfr[J0 + jj][s] = *(const bf16x8*)(
              Bb + (wn * 64 + (J0 + jj) * 16 + l16) * 128 + ((s * 64 + quad * 16) ^ xorv));
    };
    auto mfma_quad = [&](int I0, int J0) {
#pragma unroll
      for (int ii = 0; ii < 4; ++ii)
#pragma unroll
        for (int jj = 0; jj < 2; ++jj)
#pragma unroll
          for (int s = 0; s < 2; ++s)
            acc[I0 + ii][J0 + jj] = __builtin_amdgcn_mfma_f32_16x16x32_bf16(
                afr[I0 + ii][s], bfr[J0 + jj][s], acc[I0 + ii][J0 + jj], 0, 0, 0);
    };

    // ---- phase 1: read a0+b0 (12 ds_read), stage Bh0(kt+1), mfma a0*b0
    read_a(0);
    read_b(0);
    if (kt + 1 < NT) stage_b(bsel ^ 1, 0, kt + 1);
    asm volatile("s_waitcnt lgkmcnt(8)" ::: "memory");
    __builtin_amdgcn_s_barrier();
    asm volatile("s_waitcnt lgkmcnt(0)" ::: "memory");
    __builtin_amdgcn_sched_barrier(0);
    __builtin_amdgcn_s_setprio(1);
    mfma_quad(0, 0);
    __builtin_amdgcn_s_setprio(0);
    __builtin_amdgcn_s_barrier();
    // ---- phase 2: read a1, stage Bh1(kt+1), mfma a1*b0
    read_a(4);
    if (kt + 1 < NT) stage_b(bsel ^ 1, 1, kt + 1);
    __builtin_amdgcn_s_barrier();
    asm volatile("s_waitcnt lgkmcnt(0)" ::: "memory");
    __builtin_amdgcn_sched_barrier(0);
    __builtin_amdgcn_s_setprio(1);
    mfma_quad(4, 0);
    __builtin_amdgcn_s_setprio(0);
    __builtin_amdgcn_s_barrier();
    // ---- phase 3: read b1, stage Ah0(kt+2) (A reads of kt done after P2), mfma a1*b1
    read_b(2);
    if (kt + 2 < NT) stage_a(bsel, 0, kt + 2);
    __builtin_amdgcn_s_barrier();
    asm volatile("s_waitcnt lgkmcnt(0)" ::: "memory");
    __builtin_amdgcn_sched_barrier(0);
    __builtin_amdgcn_s_setprio(1);
    mfma_quad(4, 2);
    __builtin_amdgcn_s_setprio(0);
    __builtin_amdgcn_s_barrier();
    // ---- phase 4: stage Ah1(kt+2), mfma a0*b1, counted boundary wait
    if (kt + 2 < NT) stage_a(bsel, 1, kt + 2);
    __builtin_amdgcn_s_barrier();
    __builtin_amdgcn_s_setprio(1);
    mfma_quad(0, 2);
    __builtin_amdgcn_s_setprio(0);
    if (kt + 2 < NT) {
      asm volatile("s_waitcnt vmcnt(4)" ::: "memory");
    } else if (kt + 1 < NT) {
      asm volatile("s_waitcnt vmcnt(0)" ::: "memory");
    }
    __builtin_amdgcn_s_barrier();
  }

  // epilogue: C/D layout col = lane&15, row = quad*4 + reg
#pragma unroll
  for (int i = 0; i < 8; ++i)
#pragma unroll
    for (int j = 0; j < 4; ++j) {
      const int col = n0 + wn * 64 + j * 16 + l16;
#pragma unroll
      for (int r = 0; r < 4; ++r) {
        const int row = m0 + wm * 128 + i * 16 + quad * 4 + r;
        if constexpr (__is_same(OutT, float))
          C[(size_t)row * N + col] = acc[i][j][r];
        else
          C[(size_t)row * N + col] = __float2bfloat16(acc[i][j][r]);
      }
    }
}

// ---------- RMSNorm (fp32) + RoPE for q (slots 0..7) and k (slots 8..11) ----------
__global__ __launch_bounds__(64) void k_norm_rope(
    const bf16* __restrict__ qkv, const int* __restrict__ positions,
    const float* __restrict__ qw, const float* __restrict__ kw,
    bf16* __restrict__ q_r, bf16* __restrict__ k_r)
{
  const int t = blockIdx.x;
  const int slot = blockIdx.y;
  const int lane = threadIdx.x;
  const bf16* base = qkv + (size_t)t * 4096 + slot * 256;
  float x[4];
#pragma unroll
  for (int i = 0; i < 4; ++i) x[i] = __bfloat162float(base[lane + 64 * i]);
  float ss = x[0] * x[0] + x[1] * x[1] + x[2] * x[2] + x[3] * x[3];
#pragma unroll
  for (int off = 1; off < 64; off <<= 1) ss += __shfl_xor(ss, off, 64);
  const float rn = rsqrtf(ss * (1.0f / 256.0f) + 1e-6f);
  const float* w = (slot < 8) ? qw : kw;
  float nv[4];
#pragma unroll
  for (int i = 0; i < 4; ++i)
    nv[i] = x[i] * rn * (1.0f + w[lane + 64 * i]);
  const float p = (float)positions[t];
  const float C_LOG2_10K_128 = 13.287712379549449f / 128.0f;
  const float f0 = p * exp2f(-(float)lane * C_LOG2_10K_128);
  const float f1 = p * exp2f(-(float)(lane + 64) * C_LOG2_10K_128);
  const float c0 = cosf(f0), s0 = sinf(f0);
  const float c1 = cosf(f1), s1 = sinf(f1);
  const float o0 = nv[0] * c0 - nv[2] * s0;
  const float o2 = nv[2] * c0 + nv[0] * s0;
  const float o1 = nv[1] * c1 - nv[3] * s1;
  const float o3 = nv[3] * c1 + nv[1] * s1;
  bf16* dst = (slot < 8) ? (q_r + ((size_t)slot * T_SEQ + t) * 256)
                         : (k_r + ((size_t)(slot - 8) * T_SEQ + t) * 256);
  dst[lane]       = __float2bfloat16(o0);
  dst[lane + 64]  = __float2bfloat16(o1);
  dst[lane + 128] = __float2bfloat16(o2);
  dst[lane + 192] = __float2bfloat16(o3);
}

// ---------- flash attention, sliding window, GQA ----------
// q_r [8][T][256], k_r [4][T][256], vt [4][256][T], attn [T][2048]
// KVBLK=64: halves tile count (17 vs 34) -> per-tile serial latency (softmax
// chains, barriers, waits) amortized over 2x keys. R3 lesson: latency-bound,
// so keep 4-wave/256-thr blocks (8 waves/CU = 2/SIMD at 2 blocks/CU).
// Single 72KB buffer with split-stage: stage K(t+1) after post-QK barrier,
// stage V(t+1) after post-PV barrier; waits are counted (vmcnt(8) for K before
// QK, vmcnt(0) for V after softmax) so loads always have a compute phase to
// land under. XOR swizzles (all keyed by row&7 == l16&7) applied both-sides.
// Masked-row bootstrap: rows with fully-masked early tiles accumulate p=1
// garbage under mrow=-1e30; first valid tile forces rescale with
// alpha=exp(-1e30-mx)=0 which flushes it -- structurally correct.
__global__ __launch_bounds__(256, 2) void k_attn(
    const bf16* __restrict__ q_r, const bf16* __restrict__ k_r,
    const bf16* __restrict__ vt, bf16* __restrict__ attn)
{
  __shared__ bf16 Ks[64 * 256];    // 32KB [key][d], d-chunk xor (key&7)
  __shared__ bf16 Vts[256 * 64];   // 32KB [d][key], key-chunk xor (d&7)
  __shared__ bf16 Ps[4 * 16 * 64]; // 8KB per-wave P: [16 q][64 k], chunk xor (row&7)
  const int tid = threadIdx.x;
  const int w = tid >> 6;
  const int lane = tid & 63;
  const int l16 = lane & 15;
  const int quad = lane >> 4;
  const int k7 = l16 & 7;
  // XCD swizzle: head k's 64 q-tiles all land on XCD k (K/V L2-resident)
  const int bid = blockIdx.y * gridDim.x + blockIdx.x;   // 512 blocks
  const int orig = (bid & 7) * 64 + (bid >> 3);
  const int q0 = (orig & 63) * 64;
  const int h = orig >> 6;
  const int kh = h >> 1;
  const int qw0 = q0 + w * 16;   // this wave's 16 q-rows

  // Q A-fragments in registers: row l16, k = s*32 + quad*8 + j
  bf16x8 qf[8];
  {
    const bf16* qb = q_r + ((size_t)h * T_SEQ + qw0 + l16) * HD + quad * 8;
#pragma unroll
    for (int s = 0; s < 8; ++s) qf[s] = *(const bf16x8*)(qb + s * 32);
  }
  f32x4 O[16] = {};
  float mrow[4], lrow[4];
#pragma unroll
  for (int r = 0; r < 4; ++r) { mrow[r] = -1e30f; lrow[r] = 0.f; }

  // staging (256 threads, 8 gload_lds each for K and V; 4KB per instr):
  // K instr p: rows p*8+(tid>>5), chunk tid&31; pre-swz src col (tid&31)^(tid>>5)
  // V instr p: d rows p*32+(tid>>3), chunk tid&7; pre-swz src key (tid&7)^((tid>>3)&7)
  const int rK = tid >> 5;
  const int rV = tid >> 3;
  const bf16* kgb = k_r + ((size_t)kh * T_SEQ + rK) * HD + (((tid & 31) ^ rK) * 8);
  const bf16* vgb = vt + ((size_t)kh * HD + rV) * T_SEQ + (((tid & 7) ^ (rV & 7)) * 8);

  auto stage_K = [&](int j) {
    char* kl = (char*)Ks + w * 1024;
#pragma unroll
    for (int p = 0; p < 8; ++p)
      GLOAD_LDS(kgb + (size_t)(j + p * 8) * HD, kl + p * 4096);
  };
  auto stage_V = [&](int j) {
    char* vl = (char*)Vts + w * 1024;
#pragma unroll
    for (int p = 0; p < 8; ++p)
      GLOAD_LDS(vgb + (size_t)p * 32 * T_SEQ + j, vl + p * 4096);
  };

  const int jstart = (q0 >= 1024) ? (q0 - 1024) : 0;  // q0 % 64 == 0 -> aligned
  bf16* Pw = Ps + w * 1024;

  stage_K(jstart);
  stage_V(jstart);
  for (int j0 = jstart; j0 <= q0; j0 += 64) {
    asm volatile("s_waitcnt vmcnt(8)" ::: "memory");  // K(t) landed (V may be in flight)
    __builtin_amdgcn_s_barrier();

    // ---- S = Q K^T : 16 q x 64 keys (4 key-blocks), kf shared across none (16q/wave)
    f32x4 sa[4] = {};
#pragma unroll
    for (int s = 0; s < 8; ++s) {
      bf16x8 kf0 = *(const bf16x8*)((const char*)Ks + (0 * 16 + l16) * 512 + (((s * 4 + quad) ^ k7) * 16));
      bf16x8 kf1 = *(const bf16x8*)((const char*)Ks + (1 * 16 + l16) * 512 + (((s * 4 + quad) ^ k7) * 16));
      bf16x8 kf2 = *(const bf16x8*)((const char*)Ks + (2 * 16 + l16) * 512 + (((s * 4 + quad) ^ k7) * 16));
      bf16x8 kf3 = *(const bf16x8*)((const char*)Ks + (3 * 16 + l16) * 512 + (((s * 4 + quad) ^ k7) * 16));
      sa[0] = __builtin_amdgcn_mfma_f32_16x16x32_bf16(qf[s], kf0, sa[0], 0, 0, 0);
      sa[1] = __builtin_amdgcn_mfma_f32_16x16x32_bf16(qf[s], kf1, sa[1], 0, 0, 0);
      sa[2] = __builtin_amdgcn_mfma_f32_16x16x32_bf16(qf[s], kf2, sa[2], 0, 0, 0);
      sa[3] = __builtin_amdgcn_mfma_f32_16x16x32_bf16(qf[s], kf3, sa[3], 0, 0, 0);
    }

    // ---- online softmax (rows = quad*4 + r); interior fast path skips masks
    const bool interior = (j0 + 63 <= qw0) && (qw0 + 15 - j0 < WINDOW);
    float sm[4][4];
    if (interior) {
#pragma unroll
      for (int kb = 0; kb < 4; ++kb)
#pragma unroll
        for (int r = 0; r < 4; ++r) sm[kb][r] = sa[kb][r] * SM_SCALE;
    } else {
#pragma unroll
      for (int kb = 0; kb < 4; ++kb)
#pragma unroll
        for (int r = 0; r < 4; ++r) {
          const int i = qw0 + quad * 4 + r;
          const int j = j0 + kb * 16 + l16;
          sm[kb][r] = ((j <= i) && (i - j < WINDOW)) ? sa[kb][r] * SM_SCALE : -1e30f;
        }
    }
    float mx[4];
    bool ok = true;
#pragma unroll
    for (int r = 0; r < 4; ++r) {
      float m2 = fmaxf(fmaxf(sm[0][r], sm[1][r]), fmaxf(sm[2][r], sm[3][r]));
#pragma unroll
      for (int off = 1; off < 16; off <<= 1) m2 = fmaxf(m2, __shfl_xor(m2, off, 64));
      mx[r] = m2;
      ok = ok && (m2 <= mrow[r] + 8.0f);
    }
    if (!__all(ok)) {  // T13 defer-max: rescale only on >THR growth
#pragma unroll
      for (int r = 0; r < 4; ++r) {
        const float mnew = fmaxf(mrow[r], mx[r]);
        const float alpha = __expf(mrow[r] - mnew);
        lrow[r] *= alpha;
#pragma unroll
        for (int n = 0; n < 16; ++n) O[n][r] *= alpha;
        mrow[r] = mnew;
      }
    }
#pragma unroll
    for (int r = 0; r < 4; ++r) {
      const int prow = quad * 4 + r;
      float rs = 0.f;
#pragma unroll
      for (int kb = 0; kb < 4; ++kb) {
        const float p = __expf(sm[kb][r] - mrow[r]);  // bounded by e^8
        rs += p;
        Pw[prow * 64 + (((kb * 2 + (l16 >> 3)) ^ (prow & 7)) * 8) + (l16 & 7)] = __float2bfloat16(p);
      }
#pragma unroll
      for (int off = 1; off < 16; off <<= 1) rs += __shfl_xor(rs, off, 64);
      lrow[r] += rs;
    }

    asm volatile("s_waitcnt vmcnt(0)" ::: "memory");  // V(t) landed (hidden under QK+sm)
    __builtin_amdgcn_s_barrier();                     // all waves done with Ks + see V
    if (j0 < q0) stage_K(j0 + 64);                    // overwrite Ks (free after barrier)

    // ---- O += P V : P round-trip per-wave; V read [d][key] as B-frag
    asm volatile("s_waitcnt lgkmcnt(0)" ::: "memory");
    __builtin_amdgcn_sched_barrier(0);
    const bf16x8 pf0 = *(const bf16x8*)(Pw + l16 * 64 + ((quad ^ k7) * 8));
    const bf16x8 pf1 = *(const bf16x8*)(Pw + l16 * 64 + (((4 + quad) ^ k7) * 8));
#pragma unroll
    for (int n = 0; n < 16; ++n) {
      const bf16x8 vf0 = *(const bf16x8*)((const char*)Vts + (n * 16 + l16) * 128 + ((quad ^ k7) * 16));
      const bf16x8 vf1 = *(const bf16x8*)((const char*)Vts + (n * 16 + l16) * 128 + (((4 + quad) ^ k7) * 16));
      O[n] = __builtin_amdgcn_mfma_f32_16x16x32_bf16(pf0, vf0, O[n], 0, 0, 0);
      O[n] = __builtin_amdgcn_mfma_f32_16x16x32_bf16(pf1, vf1, O[n], 0, 0, 0);
    }
    __builtin_amdgcn_s_barrier();                     // all waves done with Vts
    if (j0 < q0) stage_V(j0 + 64);                    // overwrite Vts
  }
  // epilogue: O /= l, write [T][H*D]
#pragma unroll
  for (int r = 0; r < 4; ++r) {
    const float inv = 1.0f / lrow[r];
    const size_t row = qw0 + quad * 4 + r;
#pragma unroll
    for (int n = 0; n < 16; ++n)
      attn[row * (NH * HD) + h * HD + n * 16 + l16] = __float2bfloat16(O[n][r] * inv);
  }
}

extern "C" void kernel_launch(void* const* d_in, const int* in_sizes, int n_in,
                              void* d_out, int out_size, void* d_ws, size_t ws_size,
                              hipStream_t stream)
{
  const float* x  = (const float*)d_in[0];
  const int* pos  = (const int*)d_in[1];
  const float* Wq = (const float*)d_in[2];
  const float* Wk = (const float*)d_in[3];
  const float* Wv = (const float*)d_in[4];
  const float* Wo = (const float*)d_in[5];
  const float* qw = (const float*)d_in[6];
  const float* kw = (const float*)d_in[7];
  float* out = (float*)d_out;   // reference output dtype is FP32

  char* ws = (char*)d_ws;
  size_t off = 0;
  bf16* Wqkv_t = (bf16*)(ws + off); off += (size_t)4096 * 2560 * 2;  // dead after GEMM1; reused as attn_b
  bf16* Wo_t   = (bf16*)(ws + off); off += (size_t)2560 * 2048 * 2;
  bf16* qkv_b  = (bf16*)(ws + off); off += (size_t)4096 * 4096 * 2;
  bf16* q_r    = (bf16*)(ws + off); off += (size_t)8 * 4096 * 256 * 2;
  bf16* k_r    = (bf16*)(ws + off); off += (size_t)4 * 4096 * 256 * 2;
  bf16* v_t    = (bf16*)(ws + off); off += (size_t)4 * 256 * 4096 * 2;
  bf16* attn_b = Wqkv_t;
  // x_bf16 (21 MB) aliases q_r (16.8 MB) + head of k_r: x_b dies at GEMM1,
  // q_r/k_r are written only after GEMM1 completes.
  bf16* x_b = q_r;
  if (ws_size < off) return;  // insufficient workspace -> fail loudly

  // fp32 -> bf16 conversions: x elementwise, weights fused into B^T transposes
  k_f2b<<<dim3((4096 * 2560) / (256 * 8)), 256, 0, stream>>>(x, x_b);
  k_transpose_f2b<<<dim3(32, 40), 256, 0, stream>>>(Wq, Wqkv_t, 2048, 2560);
  k_transpose_f2b<<<dim3(16, 40), 256, 0, stream>>>(Wk, Wqkv_t + (size_t)2048 * 2560, 1024, 2560);
  k_transpose_f2b<<<dim3(16, 40), 256, 0, stream>>>(Wv, Wqkv_t + (size_t)3072 * 2560, 1024, 2560);
  k_transpose_f2b<<<dim3(40, 32), 256, 0, stream>>>(Wo, Wo_t, 2560, 2048);
  // fused QKV projection: [4096,2560] x [2560,4096] -> [4096,4096] (bf16 out), 256 blocks
  k_gemm8<bf16><<<dim3(16, 16), 512, 0, stream>>>(x_b, Wqkv_t, qkv_b, 4096, 4096, 2560);
  // RMSNorm + RoPE for q,k (overwrites x_b region -- x_b is dead now)
  k_norm_rope<<<dim3(4096, 12), 64, 0, stream>>>(qkv_b, pos, qw, kw, q_r, k_r);
  // V transpose: qkv_b[t][3072+kh*256+d] -> v_t[kh][d][t]
  k_transpose<<<dim3(4, 64, 4), 256, 0, stream>>>(qkv_b + 3072, v_t, 4096, 4096, 256, (long)256 * 4096);
  // flash attention: 512 blocks x 256 threads (4 waves, 16 q-rows each, KVBLK=64)
  k_attn<<<dim3(64, 8), 256, 0, stream>>>(q_r, k_r, v_t, attn_b);
  // output projection: [4096,2048] x [2048,2560] -> out (FP32 out), 160 blocks
  k_gemm8<float><<<dim3(10, 16), 512, 0, stream>>>(attn_b, Wo_t, out, 4096, 2560, 2048);
}

// Round 5
// 378.620 us; speedup vs baseline: 1.1925x; 1.0151x over previous
//
#include <hip/hip_runtime.h>
#include <hip/hip_bf16.h>

#define T_SEQ 4096
#define HIDDEN 2560
#define NH 8
#define NKV 4
#define HD 256
#define WINDOW 1024
#define SM_SCALE 0.0625f

typedef __bf16 bf16x8 __attribute__((ext_vector_type(8)));
typedef float f32x4 __attribute__((ext_vector_type(4)));
typedef __hip_bfloat16 bf16;

#define GLOAD_LDS(g, l) \
  __builtin_amdgcn_global_load_lds((const __attribute__((address_space(1))) void*)(g), \
                                   (__attribute__((address_space(3))) void*)(l), 16, 0, 0)

// ---------- fused prep: x fp32->bf16 + all 4 weight transposes (1 launch) ----------
// blocks [0,5120): f2b of x (8 elems/thread)
// blocks [5120,8960): 64x64 f2b transpose tiles of Wq/Wk/Wv (into Wqkv_t) and Wo (into Wo_t)
__global__ __launch_bounds__(256) void k_prep(
    const float* __restrict__ x,
    const float* __restrict__ Wq, const float* __restrict__ Wk,
    const float* __restrict__ Wv, const float* __restrict__ Wo,
    bf16* __restrict__ x_b, bf16* __restrict__ Wqkv_t, bf16* __restrict__ Wo_t)
{
  __shared__ bf16 t[64 * 72];  // +8 pad breaks bank conflicts on transposed read
  const int tid = threadIdx.x;
  const int b = blockIdx.x;
  if (b < 5120) {
    const size_t i = (size_t)b * 256 + tid;
    const float4 a = ((const float4*)x)[i * 2];
    const float4 c = ((const float4*)x)[i * 2 + 1];
    bf16 tmp[8];
    tmp[0] = __float2bfloat16(a.x); tmp[1] = __float2bfloat16(a.y);
    tmp[2] = __float2bfloat16(a.z); tmp[3] = __float2bfloat16(a.w);
    tmp[4] = __float2bfloat16(c.x); tmp[5] = __float2bfloat16(c.y);
    tmp[6] = __float2bfloat16(c.z); tmp[7] = __float2bfloat16(c.w);
    *(bf16x8*)(x_b + i * 8) = *(bf16x8*)tmp;
    return;
  }
  int b2 = b - 5120;
  const float* src; bf16* dst; int srs, drs, nx;
  if (b2 < 1280)      { src = Wq; dst = Wqkv_t;                        srs = 2048; drs = 2560; nx = 32; }
  else if (b2 < 1920) { b2 -= 1280; src = Wk; dst = Wqkv_t + (size_t)2048 * 2560; srs = 1024; drs = 2560; nx = 16; }
  else if (b2 < 2560) { b2 -= 1920; src = Wv; dst = Wqkv_t + (size_t)3072 * 2560; srs = 1024; drs = 2560; nx = 16; }
  else                { b2 -= 2560; src = Wo; dst = Wo_t;              srs = 2560; drs = 2048; nx = 40; }
  const int c0 = (b2 % nx) * 64;
  const int r0 = (b2 / nx) * 64;
  const int rr = tid >> 3;
  const int cc = (tid & 7) * 8;
#pragma unroll
  for (int p = 0; p < 2; ++p) {
    const float* sp = src + (size_t)(r0 + p * 32 + rr) * srs + c0 + cc;
    const float4 a = *(const float4*)sp;
    const float4 c = *(const float4*)(sp + 4);
    bf16* tp = &t[(p * 32 + rr) * 72 + cc];
    tp[0] = __float2bfloat16(a.x); tp[1] = __float2bfloat16(a.y);
    tp[2] = __float2bfloat16(a.z); tp[3] = __float2bfloat16(a.w);
    tp[4] = __float2bfloat16(c.x); tp[5] = __float2bfloat16(c.y);
    tp[6] = __float2bfloat16(c.z); tp[7] = __float2bfloat16(c.w);
  }
  __syncthreads();
#pragma unroll
  for (int p = 0; p < 2; ++p) {
    const int n = p * 32 + rr;
    bf16x8 v;
#pragma unroll
    for (int i = 0; i < 8; ++i) v[i] = ((const __bf16*)t)[(cc + i) * 72 + n];
    *(bf16x8*)(dst + (size_t)(c0 + n) * drs + r0 + cc) = v;
  }
}

// ---------- 256x256-tile bf16 GEMM, 3-phase (merged P3/P4: 6 barriers/K-tile) ----------
// T1 XCD swizzle + T2 LDS XOR-swizzle (both-sides) + counted vmcnt + T5 setprio.
// 8 waves (2Mx4N), per-wave 128x64 out, BK=64, 128KB LDS double-buffer.
// Staging: B(kt+1) halves at P1/P2, A(kt+2) both halves at P3. Boundary queue:
// A(kt+1)4 + B(kt+1)4 + A(kt+2)4 = 12 -> vmcnt(4) drains through B(kt+1).
template <typename OutT>
__global__ __launch_bounds__(512, 2) void k_gemm8(
    const bf16* __restrict__ A, const bf16* __restrict__ Bt,
    OutT* __restrict__ C, int M, int N, int K)
{
  __shared__ bf16 As[2 * 256 * 64];
  __shared__ bf16 Bs[2 * 256 * 64];
  constexpr int BUFB = 256 * 64 * 2;  // bytes per buffer

  const int tid = threadIdx.x;
  const int wave = tid >> 6;
  const int lane = tid & 63;
  const int l16 = lane & 15;
  const int quad = lane >> 4;
  const int wm = wave >> 2;   // 0..1 -> rows wm*128..+127
  const int wn = wave & 3;    // 0..3 -> cols wn*64..+63

  // XCD-aware bijective swizzle (both launches have nwg % 8 == 0)
  int id = blockIdx.y * gridDim.x + blockIdx.x;
  const int nwg = gridDim.x * gridDim.y;
  const int chunk = nwg >> 3;
  id = (id & 7) * chunk + (id >> 3);
  const int bx = id % gridDim.x;
  const int by = id / gridDim.x;
  const int m0 = by * 256;
  const int n0 = bx * 256;

  const int NT = K >> 6;           // K-tiles of 64
  const int xorv = (l16 & 7) << 4; // T2 swizzle key for fragment reads

  // staging source bases (per-lane, pre-swizzled: col chunk = (l&7)^(l>>3))
  const bf16* srcA = A + (size_t)(m0 + wave * 16 + (lane >> 3)) * K + ((lane & 7) ^ (lane >> 3)) * 8;
  const bf16* srcB = Bt + (size_t)(n0 + wave * 16 + (lane >> 3)) * K + ((lane & 7) ^ (lane >> 3)) * 8;

  auto stage_a = [&](int buf, int h, int kt) {
    const bf16* sp = srcA + (size_t)(h * 128) * K + kt * 64;
    char* dp = (char*)As + buf * BUFB + h * 16384 + wave * 2048;  // wave-uniform; HW adds lane*16
    GLOAD_LDS(sp, dp);
    GLOAD_LDS(sp + (size_t)8 * K, dp + 1024);
  };
  auto stage_b = [&](int buf, int h, int kt) {
    const bf16* sp = srcB + (size_t)(h * 128) * K + kt * 64;
    char* dp = (char*)Bs + buf * BUFB + h * 16384 + wave * 2048;
    GLOAD_LDS(sp, dp);
    GLOAD_LDS(sp + (size_t)8 * K, dp + 1024);
  };

  bf16x8 afr[8][2];  // A row-frags 0..7 x k-slice 0..1
  bf16x8 bfr[4][2];  // B col-frags 0..3 x k-slice
  f32x4 acc[8][4] = {};

  // prologue: kt0 fully, kt1 A-halves; wait for kt0 (leave 4 loads in flight)
  stage_a(0, 0, 0); stage_a(0, 1, 0);
  stage_b(0, 0, 0); stage_b(0, 1, 0);
  stage_a(1, 0, 1); stage_a(1, 1, 1);
  asm volatile("s_waitcnt vmcnt(4)" ::: "memory");
  __builtin_amdgcn_s_barrier();

  for (int kt = 0; kt < NT; ++kt) {
    const int bsel = kt & 1;
    const char* Ab = (const char*)As + bsel * BUFB;
    const char* Bb = (const char*)Bs + bsel * BUFB;

    auto read_a = [&](int I0) {
#pragma unroll
      for (int ii = 0; ii < 4; ++ii)
#pragma unroll
        for (int s = 0; s < 2; ++s)
          afr[I0 + ii][s] = *(const bf16x8*)(
              Ab + (wm * 128 + (I0 + ii) * 16 + l16) * 128 + ((s * 64 + quad * 16) ^ xorv));
    };
    auto read_b = [&](int J0) {
#pragma unroll
      for (int jj = 0; jj < 2; ++jj)
#pragma unroll
        for (int s = 0; s < 2; ++s)
          bfr[J0 + jj][s] = *(const bf16x8*)(
              Bb + (wn * 64 + (J0 + jj) * 16 + l16) * 128 + ((s * 64 + quad * 16) ^ xorv));
    };
    auto mfma_quad = [&](int I0, int J0) {
#pragma unroll
      for (int ii = 0; ii < 4; ++ii)
#pragma unroll
        for (int jj = 0; jj < 2; ++jj)
#pragma unroll
          for (int s = 0; s < 2; ++s)
            acc[I0 + ii][J0 + jj] = __builtin_amdgcn_mfma_f32_16x16x32_bf16(
                afr[I0 + ii][s], bfr[J0 + jj][s], acc[I0 + ii][J0 + jj], 0, 0, 0);
    };

    // ---- phase 1: read a0+b0 (12 ds_read), stage Bh0(kt+1), mfma a0*b0
    read_a(0);
    read_b(0);
    if (kt + 1 < NT) stage_b(bsel ^ 1, 0, kt + 1);
    asm volatile("s_waitcnt lgkmcnt(8)" ::: "memory");
    __builtin_amdgcn_s_barrier();
    asm volatile("s_waitcnt lgkmcnt(0)" ::: "memory");
    __builtin_amdgcn_sched_barrier(0);
    __builtin_amdgcn_s_setprio(1);
    mfma_quad(0, 0);
    __builtin_amdgcn_s_setprio(0);
    __builtin_amdgcn_s_barrier();
    // ---- phase 2: read a1, stage Bh1(kt+1), mfma a1*b0
    read_a(4);
    if (kt + 1 < NT) stage_b(bsel ^ 1, 1, kt + 1);
    __builtin_amdgcn_s_barrier();
    asm volatile("s_waitcnt lgkmcnt(0)" ::: "memory");
    __builtin_amdgcn_sched_barrier(0);
    __builtin_amdgcn_s_setprio(1);
    mfma_quad(4, 0);
    __builtin_amdgcn_s_setprio(0);
    __builtin_amdgcn_s_barrier();
    // ---- phase 3 (merged): read b1, stage A(kt+2) both halves (A region of bsel
    // is free after P2's end barrier), mfma a1b1 + a0b1, counted boundary wait
    read_b(2);
    if (kt + 2 < NT) { stage_a(bsel, 0, kt + 2); stage_a(bsel, 1, kt + 2); }
    __builtin_amdgcn_s_barrier();
    asm volatile("s_waitcnt lgkmcnt(0)" ::: "memory");
    __builtin_amdgcn_sched_barrier(0);
    __builtin_amdgcn_s_setprio(1);
    mfma_quad(4, 2);
    mfma_quad(0, 2);
    __builtin_amdgcn_s_setprio(0);
    if (kt + 2 < NT) {
      asm volatile("s_waitcnt vmcnt(4)" ::: "memory");
    } else if (kt + 1 < NT) {
      asm volatile("s_waitcnt vmcnt(0)" ::: "memory");
    }
    __builtin_amdgcn_s_barrier();
  }

  // epilogue: C/D layout col = lane&15, row = quad*4 + reg
#pragma unroll
  for (int i = 0; i < 8; ++i)
#pragma unroll
    for (int j = 0; j < 4; ++j) {
      const int col = n0 + wn * 64 + j * 16 + l16;
#pragma unroll
      for (int r = 0; r < 4; ++r) {
        const int row = m0 + wm * 128 + i * 16 + quad * 4 + r;
        if constexpr (__is_same(OutT, float))
          C[(size_t)row * N + col] = acc[i][j][r];
        else
          C[(size_t)row * N + col] = __float2bfloat16(acc[i][j][r]);
      }
    }
}

// ---------- fused mid: RMSNorm+RoPE (q,k) + V transpose (1 launch) ----------
// blocks [0,12288): norm+rope, 4 slots/block (t = b&4095, slot = (b>>12)*4 + wave)
// blocks [12288,13312): bf16 64x64 transpose qkv_b[t][3072+z*256+d] -> v_t[z][d][t]
__global__ __launch_bounds__(256) void k_mid(
    const bf16* __restrict__ qkv, const int* __restrict__ positions,
    const float* __restrict__ qw, const float* __restrict__ kw,
    bf16* __restrict__ q_r, bf16* __restrict__ k_r, bf16* __restrict__ v_t)
{
  __shared__ bf16 t[64 * 72];
  const int tid = threadIdx.x;
  const int b = blockIdx.x;
  if (b < 12288) {
    const int tpos = b & 4095;
    const int slot = (b >> 12) * 4 + (tid >> 6);
    const int lane = tid & 63;
    const bf16* base = qkv + (size_t)tpos * 4096 + slot * 256;
    float x[4];
#pragma unroll
    for (int i = 0; i < 4; ++i) x[i] = __bfloat162float(base[lane + 64 * i]);
    float ss = x[0] * x[0] + x[1] * x[1] + x[2] * x[2] + x[3] * x[3];
#pragma unroll
    for (int off = 1; off < 64; off <<= 1) ss += __shfl_xor(ss, off, 64);
    const float rn = rsqrtf(ss * (1.0f / 256.0f) + 1e-6f);
    const float* w = (slot < 8) ? qw : kw;
    float nv[4];
#pragma unroll
    for (int i = 0; i < 4; ++i)
      nv[i] = x[i] * rn * (1.0f + w[lane + 64 * i]);
    const float p = (float)positions[tpos];
    const float C_LOG2_10K_128 = 13.287712379549449f / 128.0f;
    const float f0 = p * exp2f(-(float)lane * C_LOG2_10K_128);
    const float f1 = p * exp2f(-(float)(lane + 64) * C_LOG2_10K_128);
    const float c0 = cosf(f0), s0 = sinf(f0);
    const float c1 = cosf(f1), s1 = sinf(f1);
    const float o0 = nv[0] * c0 - nv[2] * s0;
    const float o2 = nv[2] * c0 + nv[0] * s0;
    const float o1 = nv[1] * c1 - nv[3] * s1;
    const float o3 = nv[3] * c1 + nv[1] * s1;
    bf16* dst = (slot < 8) ? (q_r + ((size_t)slot * T_SEQ + tpos) * 256)
                           : (k_r + ((size_t)(slot - 8) * T_SEQ + tpos) * 256);
    dst[lane]       = __float2bfloat16(o0);
    dst[lane + 64]  = __float2bfloat16(o1);
    dst[lane + 128] = __float2bfloat16(o2);
    dst[lane + 192] = __float2bfloat16(o3);
    return;
  }
  const int b2 = b - 12288;
  const int c0 = (b2 & 3) * 64;          // col within [0,256) head-dim slice
  const int r0 = ((b2 >> 2) & 63) * 64;  // row (token)
  const int z = b2 >> 8;                 // kv head
  const bf16* src = qkv + 3072 + (size_t)z * 256;
  bf16* dst = v_t + (size_t)z * 256 * 4096;
  const int rr = tid >> 3;
  const int cc = (tid & 7) * 8;
#pragma unroll
  for (int p = 0; p < 2; ++p) {
    bf16x8 v = *(const bf16x8*)(src + (size_t)(r0 + p * 32 + rr) * 4096 + c0 + cc);
    *(bf16x8*)(&t[(p * 32 + rr) * 72 + cc]) = v;
  }
  __syncthreads();
#pragma unroll
  for (int p = 0; p < 2; ++p) {
    const int n = p * 32 + rr;
    bf16x8 v;
#pragma unroll
    for (int i = 0; i < 8; ++i) v[i] = ((const __bf16*)t)[(cc + i) * 72 + n];
    *(bf16x8*)(dst + (size_t)(c0 + n) * 4096 + r0 + cc) = v;
  }
}

// ---------- flash attention, sliding window, GQA (unchanged from R4) ----------
// q_r [8][T][256], k_r [4][T][256], vt [4][256][T], attn [T][2048]
// KVBLK=64, 4-wave blocks (16q/wave), single 72KB buffer, split-stage with
// counted waits; T1 per-head XCD swizzle; XOR swizzles both-sides; T13 defer-max.
__global__ __launch_bounds__(256, 2) void k_attn(
    const bf16* __restrict__ q_r, const bf16* __restrict__ k_r,
    const bf16* __restrict__ vt, bf16* __restrict__ attn)
{
  __shared__ bf16 Ks[64 * 256];    // 32KB [key][d], d-chunk xor (key&7)
  __shared__ bf16 Vts[256 * 64];   // 32KB [d][key], key-chunk xor (d&7)
  __shared__ bf16 Ps[4 * 16 * 64]; // 8KB per-wave P: [16 q][64 k], chunk xor (row&7)
  const int tid = threadIdx.x;
  const int w = tid >> 6;
  const int lane = tid & 63;
  const int l16 = lane & 15;
  const int quad = lane >> 4;
  const int k7 = l16 & 7;
  // XCD swizzle: head k's 64 q-tiles all land on XCD k (K/V L2-resident)
  const int bid = blockIdx.y * gridDim.x + blockIdx.x;   // 512 blocks
  const int orig = (bid & 7) * 64 + (bid >> 3);
  const int q0 = (orig & 63) * 64;
  const int h = orig >> 6;
  const int kh = h >> 1;
  const int qw0 = q0 + w * 16;   // this wave's 16 q-rows

  // Q A-fragments in registers: row l16, k = s*32 + quad*8 + j
  bf16x8 qf[8];
  {
    const bf16* qb = q_r + ((size_t)h * T_SEQ + qw0 + l16) * HD + quad * 8;
#pragma unroll
    for (int s = 0; s < 8; ++s) qf[s] = *(const bf16x8*)(qb + s * 32);
  }
  f32x4 O[16] = {};
  float mrow[4], lrow[4];
#pragma unroll
  for (int r = 0; r < 4; ++r) { mrow[r] = -1e30f; lrow[r] = 0.f; }

  // staging (256 threads, 8 gload_lds each for K and V; 4KB per instr):
  const int rK = tid >> 5;
  const int rV = tid >> 3;
  const bf16* kgb = k_r + ((size_t)kh * T_SEQ + rK) * HD + (((tid & 31) ^ rK) * 8);
  const bf16* vgb = vt + ((size_t)kh * HD + rV) * T_SEQ + (((tid & 7) ^ (rV & 7)) * 8);

  auto stage_K = [&](int j) {
    char* kl = (char*)Ks + w * 1024;
#pragma unroll
    for (int p = 0; p < 8; ++p)
      GLOAD_LDS(kgb + (size_t)(j + p * 8) * HD, kl + p * 4096);
  };
  auto stage_V = [&](int j) {
    char* vl = (char*)Vts + w * 1024;
#pragma unroll
    for (int p = 0; p < 8; ++p)
      GLOAD_LDS(vgb + (size_t)p * 32 * T_SEQ + j, vl + p * 4096);
  };

  const int jstart = (q0 >= 1024) ? (q0 - 1024) : 0;  // q0 % 64 == 0 -> aligned
  bf16* Pw = Ps + w * 1024;

  stage_K(jstart);
  stage_V(jstart);
  for (int j0 = jstart; j0 <= q0; j0 += 64) {
    asm volatile("s_waitcnt vmcnt(8)" ::: "memory");  // K(t) landed (V may be in flight)
    __builtin_amdgcn_s_barrier();

    // ---- S = Q K^T : 16 q x 64 keys (4 key-blocks)
    f32x4 sa[4] = {};
#pragma unroll
    for (int s = 0; s < 8; ++s) {
      bf16x8 kf0 = *(const bf16x8*)((const char*)Ks + (0 * 16 + l16) * 512 + (((s * 4 + quad) ^ k7) * 16));
      bf16x8 kf1 = *(const bf16x8*)((const char*)Ks + (1 * 16 + l16) * 512 + (((s * 4 + quad) ^ k7) * 16));
      bf16x8 kf2 = *(const bf16x8*)((const char*)Ks + (2 * 16 + l16) * 512 + (((s * 4 + quad) ^ k7) * 16));
      bf16x8 kf3 = *(const bf16x8*)((const char*)Ks + (3 * 16 + l16) * 512 + (((s * 4 + quad) ^ k7) * 16));
      sa[0] = __builtin_amdgcn_mfma_f32_16x16x32_bf16(qf[s], kf0, sa[0], 0, 0, 0);
      sa[1] = __builtin_amdgcn_mfma_f32_16x16x32_bf16(qf[s], kf1, sa[1], 0, 0, 0);
      sa[2] = __builtin_amdgcn_mfma_f32_16x16x32_bf16(qf[s], kf2, sa[2], 0, 0, 0);
      sa[3] = __builtin_amdgcn_mfma_f32_16x16x32_bf16(qf[s], kf3, sa[3], 0, 0, 0);
    }

    // ---- online softmax (rows = quad*4 + r); interior fast path skips masks
    const bool interior = (j0 + 63 <= qw0) && (qw0 + 15 - j0 < WINDOW);
    float sm[4][4];
    if (interior) {
#pragma unroll
      for (int kb = 0; kb < 4; ++kb)
#pragma unroll
        for (int r = 0; r < 4; ++r) sm[kb][r] = sa[kb][r] * SM_SCALE;
    } else {
#pragma unroll
      for (int kb = 0; kb < 4; ++kb)
#pragma unroll
        for (int r = 0; r < 4; ++r) {
          const int i = qw0 + quad * 4 + r;
          const int j = j0 + kb * 16 + l16;
          sm[kb][r] = ((j <= i) && (i - j < WINDOW)) ? sa[kb][r] * SM_SCALE : -1e30f;
        }
    }
    float mx[4];
    bool ok = true;
#pragma unroll
    for (int r = 0; r < 4; ++r) {
      float m2 = fmaxf(fmaxf(sm[0][r], sm[1][r]), fmaxf(sm[2][r], sm[3][r]));
#pragma unroll
      for (int off = 1; off < 16; off <<= 1) m2 = fmaxf(m2, __shfl_xor(m2, off, 64));
      mx[r] = m2;
      ok = ok && (m2 <= mrow[r] + 8.0f);
    }
    if (!__all(ok)) {  // T13 defer-max: rescale only on >THR growth
#pragma unroll
      for (int r = 0; r < 4; ++r) {
        const float mnew = fmaxf(mrow[r], mx[r]);
        const float alpha = __expf(mrow[r] - mnew);
        lrow[r] *= alpha;
#pragma unroll
        for (int n = 0; n < 16; ++n) O[n][r] *= alpha;
        mrow[r] = mnew;
      }
    }
#pragma unroll
    for (int r = 0; r < 4; ++r) {
      const int prow = quad * 4 + r;
      float rs = 0.f;
#pragma unroll
      for (int kb = 0; kb < 4; ++kb) {
        const float p = __expf(sm[kb][r] - mrow[r]);  // bounded by e^8
        rs += p;
        Pw[prow * 64 + (((kb * 2 + (l16 >> 3)) ^ (prow & 7)) * 8) + (l16 & 7)] = __float2bfloat16(p);
      }
#pragma unroll
      for (int off = 1; off < 16; off <<= 1) rs += __shfl_xor(rs, off, 64);
      lrow[r] += rs;
    }

    asm volatile("s_waitcnt vmcnt(0)" ::: "memory");  // V(t) landed (hidden under QK+sm)
    __builtin_amdgcn_s_barrier();                     // all waves done with Ks + see V
    if (j0 < q0) stage_K(j0 + 64);                    // overwrite Ks (free after barrier)

    // ---- O += P V : P round-trip per-wave; V read [d][key] as B-frag
    asm volatile("s_waitcnt lgkmcnt(0)" ::: "memory");
    __builtin_amdgcn_sched_barrier(0);
    const bf16x8 pf0 = *(const bf16x8*)(Pw + l16 * 64 + ((quad ^ k7) * 8));
    const bf16x8 pf1 = *(const bf16x8*)(Pw + l16 * 64 + (((4 + quad) ^ k7) * 8));
#pragma unroll
    for (int n = 0; n < 16; ++n) {
      const bf16x8 vf0 = *(const bf16x8*)((const char*)Vts + (n * 16 + l16) * 128 + ((quad ^ k7) * 16));
      const bf16x8 vf1 = *(const bf16x8*)((const char*)Vts + (n * 16 + l16) * 128 + (((4 + quad) ^ k7) * 16));
      O[n] = __builtin_amdgcn_mfma_f32_16x16x32_bf16(pf0, vf0, O[n], 0, 0, 0);
      O[n] = __builtin_amdgcn_mfma_f32_16x16x32_bf16(pf1, vf1, O[n], 0, 0, 0);
    }
    __builtin_amdgcn_s_barrier();                     // all waves done with Vts
    if (j0 < q0) stage_V(j0 + 64);                    // overwrite Vts
  }
  // epilogue: O /= l, write [T][H*D]
#pragma unroll
  for (int r = 0; r < 4; ++r) {
    const float inv = 1.0f / lrow[r];
    const size_t row = qw0 + quad * 4 + r;
#pragma unroll
    for (int n = 0; n < 16; ++n)
      attn[row * (NH * HD) + h * HD + n * 16 + l16] = __float2bfloat16(O[n][r] * inv);
  }
}

extern "C" void kernel_launch(void* const* d_in, const int* in_sizes, int n_in,
                              void* d_out, int out_size, void* d_ws, size_t ws_size,
                              hipStream_t stream)
{
  const float* x  = (const float*)d_in[0];
  const int* pos  = (const int*)d_in[1];
  const float* Wq = (const float*)d_in[2];
  const float* Wk = (const float*)d_in[3];
  const float* Wv = (const float*)d_in[4];
  const float* Wo = (const float*)d_in[5];
  const float* qw = (const float*)d_in[6];
  const float* kw = (const float*)d_in[7];
  float* out = (float*)d_out;   // reference output dtype is FP32

  char* ws = (char*)d_ws;
  size_t off = 0;
  bf16* Wqkv_t = (bf16*)(ws + off); off += (size_t)4096 * 2560 * 2;  // dead after GEMM1; reused as attn_b
  bf16* Wo_t   = (bf16*)(ws + off); off += (size_t)2560 * 2048 * 2;
  bf16* qkv_b  = (bf16*)(ws + off); off += (size_t)4096 * 4096 * 2;
  bf16* q_r    = (bf16*)(ws + off); off += (size_t)8 * 4096 * 256 * 2;
  bf16* k_r    = (bf16*)(ws + off); off += (size_t)4 * 4096 * 256 * 2;
  bf16* v_t    = (bf16*)(ws + off); off += (size_t)4 * 256 * 4096 * 2;
  bf16* attn_b = Wqkv_t;
  // x_bf16 (21 MB) aliases q_r (16.8 MB) + head of k_r: x_b dies at GEMM1,
  // q_r/k_r are written only after GEMM1 completes.
  bf16* x_b = q_r;
  if (ws_size < off) return;  // insufficient workspace -> fail loudly

  // fused prep: x f2b (5120 blocks) + 4 weight transposes (3840 tiles), 1 launch
  k_prep<<<dim3(8960), 256, 0, stream>>>(x, Wq, Wk, Wv, Wo, x_b, Wqkv_t, Wo_t);
  // fused QKV projection: [4096,2560] x [2560,4096] -> [4096,4096] (bf16 out), 256 blocks
  k_gemm8<bf16><<<dim3(16, 16), 512, 0, stream>>>(x_b, Wqkv_t, qkv_b, 4096, 4096, 2560);
  // fused mid: RMSNorm+RoPE (12288 blocks) + V transpose (1024 tiles), 1 launch
  k_mid<<<dim3(13312), 256, 0, stream>>>(qkv_b, pos, qw, kw, q_r, k_r, v_t);
  // flash attention: 512 blocks x 256 threads (4 waves, 16 q-rows each, KVBLK=64)
  k_attn<<<dim3(64, 8), 256, 0, stream>>>(q_r, k_r, v_t, attn_b);
  // output projection: [4096,2048] x [2048,2560] -> out (FP32 out), 160 blocks
  k_gemm8<float><<<dim3(10, 16), 512, 0, stream>>>(attn_b, Wo_t, out, 4096, 2560, 2048);
}

// Round 6
// 373.253 us; speedup vs baseline: 1.2097x; 1.0144x over previous
//
#include <hip/hip_runtime.h>
#include <hip/hip_bf16.h>

#define T_SEQ 4096
#define HIDDEN 2560
#define NH 8
#define NKV 4
#define HD 256
#define WINDOW 1024
#define SM_SCALE 0.0625f

typedef __bf16 bf16x8 __attribute__((ext_vector_type(8)));
typedef float f32x4 __attribute__((ext_vector_type(4)));
typedef __hip_bfloat16 bf16;

#define GLOAD_LDS(g, l) \
  __builtin_amdgcn_global_load_lds((const __attribute__((address_space(1))) void*)(g), \
                                   (__attribute__((address_space(3))) void*)(l), 16, 0, 0)

// ---------- fused prep: x fp32->bf16 + all 4 weight transposes (1 launch) ----------
// blocks [0,5120): f2b of x (8 elems/thread)
// blocks [5120,8960): 64x64 f2b transpose tiles of Wq/Wk/Wv (into Wqkv_t) and Wo (into Wo_t)
__global__ __launch_bounds__(256) void k_prep(
    const float* __restrict__ x,
    const float* __restrict__ Wq, const float* __restrict__ Wk,
    const float* __restrict__ Wv, const float* __restrict__ Wo,
    bf16* __restrict__ x_b, bf16* __restrict__ Wqkv_t, bf16* __restrict__ Wo_t)
{
  __shared__ bf16 t[64 * 72];  // +8 pad breaks bank conflicts on transposed read
  const int tid = threadIdx.x;
  const int b = blockIdx.x;
  if (b < 5120) {
    const size_t i = (size_t)b * 256 + tid;
    const float4 a = ((const float4*)x)[i * 2];
    const float4 c = ((const float4*)x)[i * 2 + 1];
    bf16 tmp[8];
    tmp[0] = __float2bfloat16(a.x); tmp[1] = __float2bfloat16(a.y);
    tmp[2] = __float2bfloat16(a.z); tmp[3] = __float2bfloat16(a.w);
    tmp[4] = __float2bfloat16(c.x); tmp[5] = __float2bfloat16(c.y);
    tmp[6] = __float2bfloat16(c.z); tmp[7] = __float2bfloat16(c.w);
    *(bf16x8*)(x_b + i * 8) = *(bf16x8*)tmp;
    return;
  }
  int b2 = b - 5120;
  const float* src; bf16* dst; int srs, drs, nx;
  if (b2 < 1280)      { src = Wq; dst = Wqkv_t;                        srs = 2048; drs = 2560; nx = 32; }
  else if (b2 < 1920) { b2 -= 1280; src = Wk; dst = Wqkv_t + (size_t)2048 * 2560; srs = 1024; drs = 2560; nx = 16; }
  else if (b2 < 2560) { b2 -= 1920; src = Wv; dst = Wqkv_t + (size_t)3072 * 2560; srs = 1024; drs = 2560; nx = 16; }
  else                { b2 -= 2560; src = Wo; dst = Wo_t;              srs = 2560; drs = 2048; nx = 40; }
  const int c0 = (b2 % nx) * 64;
  const int r0 = (b2 / nx) * 64;
  const int rr = tid >> 3;
  const int cc = (tid & 7) * 8;
#pragma unroll
  for (int p = 0; p < 2; ++p) {
    const float* sp = src + (size_t)(r0 + p * 32 + rr) * srs + c0 + cc;
    const float4 a = *(const float4*)sp;
    const float4 c = *(const float4*)(sp + 4);
    bf16* tp = &t[(p * 32 + rr) * 72 + cc];
    tp[0] = __float2bfloat16(a.x); tp[1] = __float2bfloat16(a.y);
    tp[2] = __float2bfloat16(a.z); tp[3] = __float2bfloat16(a.w);
    tp[4] = __float2bfloat16(c.x); tp[5] = __float2bfloat16(c.y);
    tp[6] = __float2bfloat16(c.z); tp[7] = __float2bfloat16(c.w);
  }
  __syncthreads();
#pragma unroll
  for (int p = 0; p < 2; ++p) {
    const int n = p * 32 + rr;
    bf16x8 v;
#pragma unroll
    for (int i = 0; i < 8; ++i) v[i] = ((const __bf16*)t)[(cc + i) * 72 + n];
    *(bf16x8*)(dst + (size_t)(c0 + n) * drs + r0 + cc) = v;
  }
}

// ---------- 256x256-tile bf16 GEMM, 3-phase, compiler-managed lgkm waits ----------
// R6 change: NO explicit lgkmcnt(0)/sched_barrier before MFMA clusters. The
// compiler emits fine-grained lgkmcnt(N) per MFMA (m97-style), so one wave's
// MFMAs overlap the block-wide LDS drain instead of waiting for it (R5 was
// fully serialized: 5328 cyc/K-tile vs ~2500 MFMA + ~2300 LDS).
// Safety: phase-end barriers + boundary vmcnt asm ("memory" clobber) enforce
// region-overwrite ordering; each phase's reads are consumed by its own MFMAs
// (data deps) before its end barrier, so staging never lands on unread data.
template <typename OutT>
__global__ __launch_bounds__(512, 2) void k_gemm8(
    const bf16* __restrict__ A, const bf16* __restrict__ Bt,
    OutT* __restrict__ C, int M, int N, int K)
{
  __shared__ bf16 As[2 * 256 * 64];
  __shared__ bf16 Bs[2 * 256 * 64];
  constexpr int BUFB = 256 * 64 * 2;  // bytes per buffer

  const int tid = threadIdx.x;
  const int wave = tid >> 6;
  const int lane = tid & 63;
  const int l16 = lane & 15;
  const int quad = lane >> 4;
  const int wm = wave >> 2;   // 0..1 -> rows wm*128..+127
  const int wn = wave & 3;    // 0..3 -> cols wn*64..+63

  // XCD-aware bijective swizzle (both launches have nwg % 8 == 0)
  int id = blockIdx.y * gridDim.x + blockIdx.x;
  const int nwg = gridDim.x * gridDim.y;
  const int chunk = nwg >> 3;
  id = (id & 7) * chunk + (id >> 3);
  const int bx = id % gridDim.x;
  const int by = id / gridDim.x;
  const int m0 = by * 256;
  const int n0 = bx * 256;

  const int NT = K >> 6;           // K-tiles of 64
  const int xorv = (l16 & 7) << 4; // T2 swizzle key for fragment reads

  // staging source bases (per-lane, pre-swizzled: col chunk = (l&7)^(l>>3))
  const bf16* srcA = A + (size_t)(m0 + wave * 16 + (lane >> 3)) * K + ((lane & 7) ^ (lane >> 3)) * 8;
  const bf16* srcB = Bt + (size_t)(n0 + wave * 16 + (lane >> 3)) * K + ((lane & 7) ^ (lane >> 3)) * 8;

  auto stage_a = [&](int buf, int h, int kt) {
    const bf16* sp = srcA + (size_t)(h * 128) * K + kt * 64;
    char* dp = (char*)As + buf * BUFB + h * 16384 + wave * 2048;  // wave-uniform; HW adds lane*16
    GLOAD_LDS(sp, dp);
    GLOAD_LDS(sp + (size_t)8 * K, dp + 1024);
  };
  auto stage_b = [&](int buf, int h, int kt) {
    const bf16* sp = srcB + (size_t)(h * 128) * K + kt * 64;
    char* dp = (char*)Bs + buf * BUFB + h * 16384 + wave * 2048;
    GLOAD_LDS(sp, dp);
    GLOAD_LDS(sp + (size_t)8 * K, dp + 1024);
  };

  bf16x8 afr[8][2];  // A row-frags 0..7 x k-slice 0..1
  bf16x8 bfr[4][2];  // B col-frags 0..3 x k-slice
  f32x4 acc[8][4] = {};

  // prologue: kt0 fully, kt1 A-halves; wait for kt0 (leave 4 loads in flight)
  stage_a(0, 0, 0); stage_a(0, 1, 0);
  stage_b(0, 0, 0); stage_b(0, 1, 0);
  stage_a(1, 0, 1); stage_a(1, 1, 1);
  asm volatile("s_waitcnt vmcnt(4)" ::: "memory");
  __builtin_amdgcn_s_barrier();

  for (int kt = 0; kt < NT; ++kt) {
    const int bsel = kt & 1;
    const char* Ab = (const char*)As + bsel * BUFB;
    const char* Bb = (const char*)Bs + bsel * BUFB;

    auto read_a = [&](int I0) {
#pragma unroll
      for (int ii = 0; ii < 4; ++ii)
#pragma unroll
        for (int s = 0; s < 2; ++s)
          afr[I0 + ii][s] = *(const bf16x8*)(
              Ab + (wm * 128 + (I0 + ii) * 16 + l16) * 128 + ((s * 64 + quad * 16) ^ xorv));
    };
    auto read_b = [&](int J0) {
#pragma unroll
      for (int jj = 0; jj < 2; ++jj)
#pragma unroll
        for (int s = 0; s < 2; ++s)
          bfr[J0 + jj][s] = *(const bf16x8*)(
              Bb + (wn * 64 + (J0 + jj) * 16 + l16) * 128 + ((s * 64 + quad * 16) ^ xorv));
    };
    auto mfma_quad = [&](int I0, int J0) {
#pragma unroll
      for (int ii = 0; ii < 4; ++ii)
#pragma unroll
        for (int jj = 0; jj < 2; ++jj)
#pragma unroll
          for (int s = 0; s < 2; ++s)
            acc[I0 + ii][J0 + jj] = __builtin_amdgcn_mfma_f32_16x16x32_bf16(
                afr[I0 + ii][s], bfr[J0 + jj][s], acc[I0 + ii][J0 + jj], 0, 0, 0);
    };

    // ---- phase 1: read a0+b0 (12 ds_read), stage Bh0(kt+1), mfma a0*b0
    read_a(0);
    read_b(0);
    if (kt + 1 < NT) stage_b(bsel ^ 1, 0, kt + 1);
    __builtin_amdgcn_s_barrier();
    __builtin_amdgcn_s_setprio(1);
    mfma_quad(0, 0);
    __builtin_amdgcn_s_setprio(0);
    __builtin_amdgcn_s_barrier();
    // ---- phase 2: read a1, stage Bh1(kt+1), mfma a1*b0
    read_a(4);
    if (kt + 1 < NT) stage_b(bsel ^ 1, 1, kt + 1);
    __builtin_amdgcn_s_barrier();
    __builtin_amdgcn_s_setprio(1);
    mfma_quad(4, 0);
    __builtin_amdgcn_s_setprio(0);
    __builtin_amdgcn_s_barrier();
    // ---- phase 3 (merged): read b1, stage A(kt+2) both halves (A region of bsel
    // is free after P2's end barrier), mfma a1b1 + a0b1, counted boundary wait
    read_b(2);
    if (kt + 2 < NT) { stage_a(bsel, 0, kt + 2); stage_a(bsel, 1, kt + 2); }
    __builtin_amdgcn_s_barrier();
    __builtin_amdgcn_s_setprio(1);
    mfma_quad(4, 2);
    mfma_quad(0, 2);
    __builtin_amdgcn_s_setprio(0);
    if (kt + 2 < NT) {
      asm volatile("s_waitcnt vmcnt(4)" ::: "memory");
    } else if (kt + 1 < NT) {
      asm volatile("s_waitcnt vmcnt(0)" ::: "memory");
    }
    __builtin_amdgcn_s_barrier();
  }

  // epilogue: C/D layout col = lane&15, row = quad*4 + reg
#pragma unroll
  for (int i = 0; i < 8; ++i)
#pragma unroll
    for (int j = 0; j < 4; ++j) {
      const int col = n0 + wn * 64 + j * 16 + l16;
#pragma unroll
      for (int r = 0; r < 4; ++r) {
        const int row = m0 + wm * 128 + i * 16 + quad * 4 + r;
        if constexpr (__is_same(OutT, float))
          C[(size_t)row * N + col] = acc[i][j][r];
        else
          C[(size_t)row * N + col] = __float2bfloat16(acc[i][j][r]);
      }
    }
}

// ---------- fused mid: RMSNorm+RoPE (q,k) + V transpose (1 launch) ----------
// blocks [0,12288): norm+rope, 4 slots/block (t = b&4095, slot = (b>>12)*4 + wave)
// blocks [12288,13312): bf16 64x64 transpose qkv_b[t][3072+z*256+d] -> v_t[z][d][t]
__global__ __launch_bounds__(256) void k_mid(
    const bf16* __restrict__ qkv, const int* __restrict__ positions,
    const float* __restrict__ qw, const float* __restrict__ kw,
    bf16* __restrict__ q_r, bf16* __restrict__ k_r, bf16* __restrict__ v_t)
{
  __shared__ bf16 t[64 * 72];
  const int tid = threadIdx.x;
  const int b = blockIdx.x;
  if (b < 12288) {
    const int tpos = b & 4095;
    const int slot = (b >> 12) * 4 + (tid >> 6);
    const int lane = tid & 63;
    const bf16* base = qkv + (size_t)tpos * 4096 + slot * 256;
    float x[4];
#pragma unroll
    for (int i = 0; i < 4; ++i) x[i] = __bfloat162float(base[lane + 64 * i]);
    float ss = x[0] * x[0] + x[1] * x[1] + x[2] * x[2] + x[3] * x[3];
#pragma unroll
    for (int off = 1; off < 64; off <<= 1) ss += __shfl_xor(ss, off, 64);
    const float rn = rsqrtf(ss * (1.0f / 256.0f) + 1e-6f);
    const float* w = (slot < 8) ? qw : kw;
    float nv[4];
#pragma unroll
    for (int i = 0; i < 4; ++i)
      nv[i] = x[i] * rn * (1.0f + w[lane + 64 * i]);
    const float p = (float)positions[tpos];
    const float C_LOG2_10K_128 = 13.287712379549449f / 128.0f;
    const float f0 = p * exp2f(-(float)lane * C_LOG2_10K_128);
    const float f1 = p * exp2f(-(float)(lane + 64) * C_LOG2_10K_128);
    const float c0 = cosf(f0), s0 = sinf(f0);
    const float c1 = cosf(f1), s1 = sinf(f1);
    const float o0 = nv[0] * c0 - nv[2] * s0;
    const float o2 = nv[2] * c0 + nv[0] * s0;
    const float o1 = nv[1] * c1 - nv[3] * s1;
    const float o3 = nv[3] * c1 + nv[1] * s1;
    bf16* dst = (slot < 8) ? (q_r + ((size_t)slot * T_SEQ + tpos) * 256)
                           : (k_r + ((size_t)(slot - 8) * T_SEQ + tpos) * 256);
    dst[lane]       = __float2bfloat16(o0);
    dst[lane + 64]  = __float2bfloat16(o1);
    dst[lane + 128] = __float2bfloat16(o2);
    dst[lane + 192] = __float2bfloat16(o3);
    return;
  }
  const int b2 = b - 12288;
  const int c0 = (b2 & 3) * 64;          // col within [0,256) head-dim slice
  const int r0 = ((b2 >> 2) & 63) * 64;  // row (token)
  const int z = b2 >> 8;                 // kv head
  const bf16* src = qkv + 3072 + (size_t)z * 256;
  bf16* dst = v_t + (size_t)z * 256 * 4096;
  const int rr = tid >> 3;
  const int cc = (tid & 7) * 8;
#pragma unroll
  for (int p = 0; p < 2; ++p) {
    bf16x8 v = *(const bf16x8*)(src + (size_t)(r0 + p * 32 + rr) * 4096 + c0 + cc);
    *(bf16x8*)(&t[(p * 32 + rr) * 72 + cc]) = v;
  }
  __syncthreads();
#pragma unroll
  for (int p = 0; p < 2; ++p) {
    const int n = p * 32 + rr;
    bf16x8 v;
#pragma unroll
    for (int i = 0; i < 8; ++i) v[i] = ((const __bf16*)t)[(cc + i) * 72 + n];
    *(bf16x8*)(dst + (size_t)(c0 + n) * 4096 + r0 + cc) = v;
  }
}

// ---------- flash attention, sliding window, GQA (unchanged from R4) ----------
// q_r [8][T][256], k_r [4][T][256], vt [4][256][T], attn [T][2048]
// KVBLK=64, 4-wave blocks (16q/wave), single 72KB buffer, split-stage with
// counted waits; T1 per-head XCD swizzle; XOR swizzles both-sides; T13 defer-max.
__global__ __launch_bounds__(256, 2) void k_attn(
    const bf16* __restrict__ q_r, const bf16* __restrict__ k_r,
    const bf16* __restrict__ vt, bf16* __restrict__ attn)
{
  __shared__ bf16 Ks[64 * 256];    // 32KB [key][d], d-chunk xor (key&7)
  __shared__ bf16 Vts[256 * 64];   // 32KB [d][key], key-chunk xor (d&7)
  __shared__ bf16 Ps[4 * 16 * 64]; // 8KB per-wave P: [16 q][64 k], chunk xor (row&7)
  const int tid = threadIdx.x;
  const int w = tid >> 6;
  const int lane = tid & 63;
  const int l16 = lane & 15;
  const int quad = lane >> 4;
  const int k7 = l16 & 7;
  // XCD swizzle: head k's 64 q-tiles all land on XCD k (K/V L2-resident)
  const int bid = blockIdx.y * gridDim.x + blockIdx.x;   // 512 blocks
  const int orig = (bid & 7) * 64 + (bid >> 3);
  const int q0 = (orig & 63) * 64;
  const int h = orig >> 6;
  const int kh = h >> 1;
  const int qw0 = q0 + w * 16;   // this wave's 16 q-rows

  // Q A-fragments in registers: row l16, k = s*32 + quad*8 + j
  bf16x8 qf[8];
  {
    const bf16* qb = q_r + ((size_t)h * T_SEQ + qw0 + l16) * HD + quad * 8;
#pragma unroll
    for (int s = 0; s < 8; ++s) qf[s] = *(const bf16x8*)(qb + s * 32);
  }
  f32x4 O[16] = {};
  float mrow[4], lrow[4];
#pragma unroll
  for (int r = 0; r < 4; ++r) { mrow[r] = -1e30f; lrow[r] = 0.f; }

  // staging (256 threads, 8 gload_lds each for K and V; 4KB per instr):
  const int rK = tid >> 5;
  const int rV = tid >> 3;
  const bf16* kgb = k_r + ((size_t)kh * T_SEQ + rK) * HD + (((tid & 31) ^ rK) * 8);
  const bf16* vgb = vt + ((size_t)kh * HD + rV) * T_SEQ + (((tid & 7) ^ (rV & 7)) * 8);

  auto stage_K = [&](int j) {
    char* kl = (char*)Ks + w * 1024;
#pragma unroll
    for (int p = 0; p < 8; ++p)
      GLOAD_LDS(kgb + (size_t)(j + p * 8) * HD, kl + p * 4096);
  };
  auto stage_V = [&](int j) {
    char* vl = (char*)Vts + w * 1024;
#pragma unroll
    for (int p = 0; p < 8; ++p)
      GLOAD_LDS(vgb + (size_t)p * 32 * T_SEQ + j, vl + p * 4096);
  };

  const int jstart = (q0 >= 1024) ? (q0 - 1024) : 0;  // q0 % 64 == 0 -> aligned
  bf16* Pw = Ps + w * 1024;

  stage_K(jstart);
  stage_V(jstart);
  for (int j0 = jstart; j0 <= q0; j0 += 64) {
    asm volatile("s_waitcnt vmcnt(8)" ::: "memory");  // K(t) landed (V may be in flight)
    __builtin_amdgcn_s_barrier();

    // ---- S = Q K^T : 16 q x 64 keys (4 key-blocks)
    f32x4 sa[4] = {};
#pragma unroll
    for (int s = 0; s < 8; ++s) {
      bf16x8 kf0 = *(const bf16x8*)((const char*)Ks + (0 * 16 + l16) * 512 + (((s * 4 + quad) ^ k7) * 16));
      bf16x8 kf1 = *(const bf16x8*)((const char*)Ks + (1 * 16 + l16) * 512 + (((s * 4 + quad) ^ k7) * 16));
      bf16x8 kf2 = *(const bf16x8*)((const char*)Ks + (2 * 16 + l16) * 512 + (((s * 4 + quad) ^ k7) * 16));
      bf16x8 kf3 = *(const bf16x8*)((const char*)Ks + (3 * 16 + l16) * 512 + (((s * 4 + quad) ^ k7) * 16));
      sa[0] = __builtin_amdgcn_mfma_f32_16x16x32_bf16(qf[s], kf0, sa[0], 0, 0, 0);
      sa[1] = __builtin_amdgcn_mfma_f32_16x16x32_bf16(qf[s], kf1, sa[1], 0, 0, 0);
      sa[2] = __builtin_amdgcn_mfma_f32_16x16x32_bf16(qf[s], kf2, sa[2], 0, 0, 0);
      sa[3] = __builtin_amdgcn_mfma_f32_16x16x32_bf16(qf[s], kf3, sa[3], 0, 0, 0);
    }

    // ---- online softmax (rows = quad*4 + r); interior fast path skips masks
    const bool interior = (j0 + 63 <= qw0) && (qw0 + 15 - j0 < WINDOW);
    float sm[4][4];
    if (interior) {
#pragma unroll
      for (int kb = 0; kb < 4; ++kb)
#pragma unroll
        for (int r = 0; r < 4; ++r) sm[kb][r] = sa[kb][r] * SM_SCALE;
    } else {
#pragma unroll
      for (int kb = 0; kb < 4; ++kb)
#pragma unroll
        for (int r = 0; r < 4; ++r) {
          const int i = qw0 + quad * 4 + r;
          const int j = j0 + kb * 16 + l16;
          sm[kb][r] = ((j <= i) && (i - j < WINDOW)) ? sa[kb][r] * SM_SCALE : -1e30f;
        }
    }
    float mx[4];
    bool ok = true;
#pragma unroll
    for (int r = 0; r < 4; ++r) {
      float m2 = fmaxf(fmaxf(sm[0][r], sm[1][r]), fmaxf(sm[2][r], sm[3][r]));
#pragma unroll
      for (int off = 1; off < 16; off <<= 1) m2 = fmaxf(m2, __shfl_xor(m2, off, 64));
      mx[r] = m2;
      ok = ok && (m2 <= mrow[r] + 8.0f);
    }
    if (!__all(ok)) {  // T13 defer-max: rescale only on >THR growth
#pragma unroll
      for (int r = 0; r < 4; ++r) {
        const float mnew = fmaxf(mrow[r], mx[r]);
        const float alpha = __expf(mrow[r] - mnew);
        lrow[r] *= alpha;
#pragma unroll
        for (int n = 0; n < 16; ++n) O[n][r] *= alpha;
        mrow[r] = mnew;
      }
    }
#pragma unroll
    for (int r = 0; r < 4; ++r) {
      const int prow = quad * 4 + r;
      float rs = 0.f;
#pragma unroll
      for (int kb = 0; kb < 4; ++kb) {
        const float p = __expf(sm[kb][r] - mrow[r]);  // bounded by e^8
        rs += p;
        Pw[prow * 64 + (((kb * 2 + (l16 >> 3)) ^ (prow & 7)) * 8) + (l16 & 7)] = __float2bfloat16(p);
      }
#pragma unroll
      for (int off = 1; off < 16; off <<= 1) rs += __shfl_xor(rs, off, 64);
      lrow[r] += rs;
    }

    asm volatile("s_waitcnt vmcnt(0)" ::: "memory");  // V(t) landed (hidden under QK+sm)
    __builtin_amdgcn_s_barrier();                     // all waves done with Ks + see V
    if (j0 < q0) stage_K(j0 + 64);                    // overwrite Ks (free after barrier)

    // ---- O += P V : P round-trip per-wave; V read [d][key] as B-frag
    asm volatile("s_waitcnt lgkmcnt(0)" ::: "memory");
    __builtin_amdgcn_sched_barrier(0);
    const bf16x8 pf0 = *(const bf16x8*)(Pw + l16 * 64 + ((quad ^ k7) * 8));
    const bf16x8 pf1 = *(const bf16x8*)(Pw + l16 * 64 + (((4 + quad) ^ k7) * 8));
#pragma unroll
    for (int n = 0; n < 16; ++n) {
      const bf16x8 vf0 = *(const bf16x8*)((const char*)Vts + (n * 16 + l16) * 128 + ((quad ^ k7) * 16));
      const bf16x8 vf1 = *(const bf16x8*)((const char*)Vts + (n * 16 + l16) * 128 + (((4 + quad) ^ k7) * 16));
      O[n] = __builtin_amdgcn_mfma_f32_16x16x32_bf16(pf0, vf0, O[n], 0, 0, 0);
      O[n] = __builtin_amdgcn_mfma_f32_16x16x32_bf16(pf1, vf1, O[n], 0, 0, 0);
    }
    __builtin_amdgcn_s_barrier();                     // all waves done with Vts
    if (j0 < q0) stage_V(j0 + 64);                    // overwrite Vts
  }
  // epilogue: O /= l, write [T][H*D]
#pragma unroll
  for (int r = 0; r < 4; ++r) {
    const float inv = 1.0f / lrow[r];
    const size_t row = qw0 + quad * 4 + r;
#pragma unroll
    for (int n = 0; n < 16; ++n)
      attn[row * (NH * HD) + h * HD + n * 16 + l16] = __float2bfloat16(O[n][r] * inv);
  }
}

extern "C" void kernel_launch(void* const* d_in, const int* in_sizes, int n_in,
                              void* d_out, int out_size, void* d_ws, size_t ws_size,
                              hipStream_t stream)
{
  const float* x  = (const float*)d_in[0];
  const int* pos  = (const int*)d_in[1];
  const float* Wq = (const float*)d_in[2];
  const float* Wk = (const float*)d_in[3];
  const float* Wv = (const float*)d_in[4];
  const float* Wo = (const float*)d_in[5];
  const float* qw = (const float*)d_in[6];
  const float* kw = (const float*)d_in[7];
  float* out = (float*)d_out;   // reference output dtype is FP32

  char* ws = (char*)d_ws;
  size_t off = 0;
  bf16* Wqkv_t = (bf16*)(ws + off); off += (size_t)4096 * 2560 * 2;  // dead after GEMM1; reused as attn_b
  bf16* Wo_t   = (bf16*)(ws + off); off += (size_t)2560 * 2048 * 2;
  bf16* qkv_b  = (bf16*)(ws + off); off += (size_t)4096 * 4096 * 2;
  bf16* q_r    = (bf16*)(ws + off); off += (size_t)8 * 4096 * 256 * 2;
  bf16* k_r    = (bf16*)(ws + off); off += (size_t)4 * 4096 * 256 * 2;
  bf16* v_t    = (bf16*)(ws + off); off += (size_t)4 * 256 * 4096 * 2;
  bf16* attn_b = Wqkv_t;
  // x_bf16 (21 MB) aliases q_r (16.8 MB) + head of k_r: x_b dies at GEMM1,
  // q_r/k_r are written only after GEMM1 completes.
  bf16* x_b = q_r;
  if (ws_size < off) return;  // insufficient workspace -> fail loudly

  // fused prep: x f2b (5120 blocks) + 4 weight transposes (3840 tiles), 1 launch
  k_prep<<<dim3(8960), 256, 0, stream>>>(x, Wq, Wk, Wv, Wo, x_b, Wqkv_t, Wo_t);
  // fused QKV projection: [4096,2560] x [2560,4096] -> [4096,4096] (bf16 out), 256 blocks
  k_gemm8<bf16><<<dim3(16, 16), 512, 0, stream>>>(x_b, Wqkv_t, qkv_b, 4096, 4096, 2560);
  // fused mid: RMSNorm+RoPE (12288 blocks) + V transpose (1024 tiles), 1 launch
  k_mid<<<dim3(13312), 256, 0, stream>>>(qkv_b, pos, qw, kw, q_r, k_r, v_t);
  // flash attention: 512 blocks x 256 threads (4 waves, 16 q-rows each, KVBLK=64)
  k_attn<<<dim3(64, 8), 256, 0, stream>>>(q_r, k_r, v_t, attn_b);
  // output projection: [4096,2048] x [2048,2560] -> out (FP32 out), 160 blocks
  k_gemm8<float><<<dim3(10, 16), 512, 0, stream>>>(attn_b, Wo_t, out, 4096, 2560, 2048);
}